// Round 2
// baseline (362.733 us; speedup 1.0000x reference)
//
#include <hip/hip_runtime.h>
#include <hip/hip_fp16.h>
#include <math.h>

#define B_ 2
#define N_ 6400
#define E_ 256
#define C_ 6
#define L_ 4
#define SL2_ 128  // 2-channel slices (E/2)

// Level geometry (H, W), flattened per-channel offsets, total pixels/channel
__device__ __host__ constexpr int HWH[4] = {64, 32, 16, 8};
__device__ __host__ constexpr int HWW[4] = {176, 88, 44, 22};
__device__ __host__ constexpr int LOFF[4] = {0, 11264, 14080, 14784};
#define HWT 14960

struct __align__(8) H4 { __half2 lo, hi; };   // 4 fp16 values

typedef __attribute__((ext_vector_type(8))) _Float16 half8;
typedef __attribute__((ext_vector_type(4))) _Float16 half4;
typedef __attribute__((ext_vector_type(4))) float floatx4;

// ---------------------------------------------------------------------------
// Kernel 1: per-point prep. (unchanged)
// ---------------------------------------------------------------------------
__global__ __launch_bounds__(256) void prep_kernel(
    const float* __restrict__ inst, const float* __restrict__ anchor,
    const float* __restrict__ proj, const float* __restrict__ attn_w,
    const float* __restrict__ attn_b,
    uint4* __restrict__ meta_w, int4* __restrict__ meta_b)
{
    __shared__ float AWT[256 * 24];   // attn_w transposed [k][j]
    __shared__ float ts[256 * 33];    // inst tile [point][k-chunk], padded

    const int tid = threadIdx.x;

    for (int idx = tid; idx < 24 * 256; idx += 256) {
        int j = idx >> 8, k = idx & 255;
        AWT[k * 24 + j] = attn_w[idx];
    }
    __syncthreads();

    const int pt0 = blockIdx.x * 256;

    float acc[24];
#pragma unroll
    for (int j = 0; j < 24; j++) acc[j] = attn_b[j];

    for (int k0 = 0; k0 < 256; k0 += 32) {
#pragma unroll
        for (int r = 0; r < 32; r++) {
            int lin = r * 256 + tid;
            int p = lin >> 5, kk = lin & 31;
            ts[p * 33 + kk] = inst[(size_t)(pt0 + p) * 256 + k0 + kk];
        }
        __syncthreads();
#pragma unroll
        for (int kk = 0; kk < 32; kk++) {
            float v = ts[tid * 33 + kk];
            const float* aw = &AWT[(k0 + kk) * 24];
#pragma unroll
            for (int j = 0; j < 24; j++) acc[j] += v * aw[j];
        }
        __syncthreads();
    }

    const int pt = pt0 + tid;
    const int b = pt / N_;   // uniform per block (6400 % 256 == 0)
    const int n = pt - b * N_;

    float attn[24];
#pragma unroll
    for (int c = 0; c < C_; c++) {
        float m = fmaxf(fmaxf(acc[c * 4], acc[c * 4 + 1]),
                        fmaxf(acc[c * 4 + 2], acc[c * 4 + 3]));
        float s = 0.f;
#pragma unroll
        for (int l = 0; l < L_; l++) {
            float e = expf(acc[c * 4 + l] - m);
            attn[c * 4 + l] = e;
            s += e;
        }
        float r = 1.f / s;
#pragma unroll
        for (int l = 0; l < L_; l++) attn[c * 4 + l] *= r;
    }

    float ax = anchor[(size_t)pt * 11 + 0];
    float ay = anchor[(size_t)pt * 11 + 1];
    float az = anchor[(size_t)pt * 11 + 2];
    float wxp = (1.f / (1.f + expf(-ax))) * 102.4f - 51.2f;
    float wyp = (1.f / (1.f + expf(-ay))) * 102.4f - 51.2f;
    float wzp = (1.f / (1.f + expf(-az))) * 8.f - 5.f;

#pragma unroll
    for (int c = 0; c < C_; c++) {
        const float* P = &proj[(size_t)(b * C_ + c) * 16];
        float cx = P[0] * wxp + P[1] * wyp + P[2] * wzp + P[3];
        float cy = P[4] * wxp + P[5] * wyp + P[6] * wzp + P[7];
        float cz = P[8] * wxp + P[9] * wyp + P[10] * wzp + P[11];
        float d = fmaxf(cz, 1e-4f);
        float u = cx / d, v = cy / d;

        float x0f = floorf(u), y0f = floorf(v);
        float fx1 = u - x0f, fy1 = v - y0f;
        float fx0 = 1.f - fx1, fy0 = 1.f - fy1;

        float4 wl[4]; int bsx[4];
#pragma unroll
        for (int l = 0; l < L_; l++) {
            const int W = HWW[l], H = HWH[l];
            float ax0, ax1; int bx;
            int ix = (int)fminf(fmaxf(x0f, -2.f), (float)W);
            if (ix <= -2 || ix >= W)      { ax0 = 0.f;  ax1 = 0.f;  bx = 0; }
            else if (ix == -1)            { ax0 = fx1;  ax1 = 0.f;  bx = 0; }
            else if (ix == W - 1)         { ax0 = 0.f;  ax1 = fx0;  bx = W - 2; }
            else                          { ax0 = fx0;  ax1 = fx1;  bx = ix; }
            float ay0, ay1; int by;
            int iy = (int)fminf(fmaxf(y0f, -2.f), (float)H);
            if (iy <= -2 || iy >= H)      { ay0 = 0.f;  ay1 = 0.f;  by = 0; }
            else if (iy == -1)            { ay0 = fy1;  ay1 = 0.f;  by = 0; }
            else if (iy == H - 1)         { ay0 = 0.f;  ay1 = fy0;  by = H - 2; }
            else                          { ay0 = fy0;  ay1 = fy1;  by = iy; }

            float a = attn[c * 4 + l];
            wl[l] = make_float4(a * ay0 * ax0, a * ay0 * ax1,
                                a * ay1 * ax0, a * ay1 * ax1);
            bsx[l] = by * W + bx;
        }
        size_t mi = (size_t)(b * C_ + c) * N_ + n;
        union { uint4 u; __half2 h[4]; } q0, q1;
        q0.h[0] = __floats2half2_rn(wl[0].x, wl[0].y);
        q0.h[1] = __floats2half2_rn(wl[0].z, wl[0].w);
        q0.h[2] = __floats2half2_rn(wl[1].x, wl[1].y);
        q0.h[3] = __floats2half2_rn(wl[1].z, wl[1].w);
        q1.h[0] = __floats2half2_rn(wl[2].x, wl[2].y);
        q1.h[1] = __floats2half2_rn(wl[2].z, wl[2].w);
        q1.h[2] = __floats2half2_rn(wl[3].x, wl[3].y);
        q1.h[3] = __floats2half2_rn(wl[3].z, wl[3].w);
        meta_w[mi * 2 + 0] = q0.u;
        meta_w[mi * 2 + 1] = q1.u;
        meta_b[mi] = make_int4(bsx[0], bsx[1], bsx[2], bsx[3]);
    }
}

// ---------------------------------------------------------------------------
// Kernel 1.5: visibility compaction, OUT OF PLACE (value-idempotent across
// launches: meta is never mutated after prep; cmeta/counts get identical
// deterministic values every launch). One block per (b,c) segment; keeps
// entries with any nonzero fp16 weight (weights >= +0, so bitwise-zero test
// is exact). Compacted cmeta_b: {bsx0|bsx1<<16, bsx2|bsx3<<16, orig_n, 0}.
// ---------------------------------------------------------------------------
__global__ __launch_bounds__(1024) void compact_kernel(
    const uint4* __restrict__ meta_w, const int4* __restrict__ meta_b,
    uint4* __restrict__ cmeta_w, int4* __restrict__ cmeta_b,
    int* __restrict__ counts)
{
    const int seg = blockIdx.x;               // b*C + c, 0..11
    const size_t base = (size_t)seg * N_;
    __shared__ int wsum[17];

    const int tid = threadIdx.x;
    const int lane = tid & 63;
    const int wv = tid >> 6;

    int running = 0;
    for (int c0 = 0; c0 < N_; c0 += 1024) {
        const int n = c0 + tid;
        const bool valid = n < N_;
        uint4 m0 = make_uint4(0, 0, 0, 0), m1 = make_uint4(0, 0, 0, 0);
        int4 bx = make_int4(0, 0, 0, 0);
        if (valid) {
            m0 = meta_w[(base + n) * 2];
            m1 = meta_w[(base + n) * 2 + 1];
            bx = meta_b[base + n];
        }
        const bool vis = valid &&
            ((m0.x | m0.y | m0.z | m0.w | m1.x | m1.y | m1.z | m1.w) != 0u);

        unsigned long long ball = __ballot(vis);
        int wpre = __popcll(ball & ((1ull << lane) - 1ull));
        if (lane == 0) wsum[wv] = __popcll(ball);
        __syncthreads();
        if (tid == 0) {
            int r = 0;
#pragma unroll
            for (int w = 0; w < 16; w++) { int t = wsum[w]; wsum[w] = r; r += t; }
            wsum[16] = r;
        }
        __syncthreads();
        const int pos = running + wsum[wv] + wpre;
        const int ctot = wsum[16];

        if (vis) {
            cmeta_w[(base + pos) * 2]     = m0;
            cmeta_w[(base + pos) * 2 + 1] = m1;
            cmeta_b[base + pos] = make_int4(bx.x | (bx.y << 16),
                                            bx.z | (bx.w << 16), n, 0);
        }
        running += ctot;
        __syncthreads();   // wsum reused next chunk
    }
    if (tid == 0) counts[seg] = running;
}

// ---------------------------------------------------------------------------
// Kernel 2 (compacted main path): gather over visible points only.
// Block = (b, cam, 2-channel slice). Zero-fills its own pout slice (overlaps
// LDS staging), stages channel planes as fp16 in LDS, then iterates the
// compacted list: branch-free 4-level gather, per-level accumulator trees,
// scattered-but-monotonic 4 B store at the original point index.
// ---------------------------------------------------------------------------
__global__ __launch_bounds__(1024) void gather_compact(
    const float* __restrict__ f0, const float* __restrict__ f1,
    const float* __restrict__ f2, const float* __restrict__ f3,
    const uint4* __restrict__ cmeta_w, const int4* __restrict__ cmeta_b,
    const int* __restrict__ counts, __half2* __restrict__ part2)
{
    __shared__ __half2 lds2[HWT];   // 59840 B

    const int tid = threadIdx.x;
    const int bid = blockIdx.x;
    const int slice = bid & 127;         // E/2 = 128 slices
    const int c = (bid >> 7) % C_;
    const int b = bid / (128 * C_);
    const int e0 = slice * 2;
    const int bc = b * C_ + c;

    __half2* pout = part2 + ((size_t)bc * SL2_ + slice) * N_;

    // zero own slice: 6400 * 4 B = 1600 uint4 stores (16B-aligned)
    for (int z = tid; z < 1600; z += 1024)
        ((uint4*)pout)[z] = make_uint4(0, 0, 0, 0);

    const float* fs[4] = {f0, f1, f2, f3};

#pragma unroll
    for (int l = 0; l < L_; l++) {
        const int HW = HWH[l] * HWW[l];
        const float* s0 = fs[l] + (size_t)(bc * E_ + e0) * HW;
        const float* s1 = s0 + HW;
        const int quarter = HW >> 2;
        for (int q = tid; q < quarter; q += 1024) {
            int p = q * 4;
            float4 v0 = *(const float4*)(s0 + p);
            float4 v1 = *(const float4*)(s1 + p);
            union { uint4 u; __half2 h[4]; } pk;
            pk.h[0] = __floats2half2_rn(v0.x, v1.x);
            pk.h[1] = __floats2half2_rn(v0.y, v1.y);
            pk.h[2] = __floats2half2_rn(v0.z, v1.z);
            pk.h[3] = __floats2half2_rn(v0.w, v1.w);
            *(uint4*)&lds2[LOFF[l] + p] = pk.u;
        }
    }
    __syncthreads();

    const int nvis = counts[bc];
    const uint4* mwp = cmeta_w + (size_t)bc * N_ * 2;
    const int4* mbp = cmeta_b + (size_t)bc * N_;

    int i = tid;
    uint4 m0, m1; int4 cb;
    if (i < nvis) {
        m0 = mwp[(size_t)i * 2];
        m1 = mwp[(size_t)i * 2 + 1];
        cb = mbp[i];
    }

    while (i < nvis) {
        int ii = i + 1024;
        uint4 t0, t1; int4 tb;
        if (ii < nvis) {
            t0 = mwp[(size_t)ii * 2];
            t1 = mwp[(size_t)ii * 2 + 1];
            tb = mbp[ii];
        }

        union { uint4 u; __half2 h[4]; } a0u, a1u;
        a0u.u = m0; a1u.u = m1;
        __half2 wh[8];
        wh[0] = a0u.h[0]; wh[1] = a0u.h[1]; wh[2] = a0u.h[2]; wh[3] = a0u.h[3];
        wh[4] = a1u.h[0]; wh[5] = a1u.h[1]; wh[6] = a1u.h[2]; wh[7] = a1u.h[3];

        int bs[4];
        bs[0] = cb.x & 0xffff;
        bs[1] = ((unsigned)cb.x) >> 16;
        bs[2] = cb.y & 0xffff;
        bs[3] = ((unsigned)cb.y) >> 16;
        const int outn = cb.z;

        float p0[4], p1[4];
#pragma unroll
        for (int l = 0; l < L_; l++) {
            const int W = HWW[l];
            const int base = LOFF[l] + bs[l];
            float2 wab = __half22float2(wh[l * 2]);      // w00, w01
            float2 wcd = __half22float2(wh[l * 2 + 1]);  // w10, w11
            float2 f00 = __half22float2(lds2[base]);
            float2 f01 = __half22float2(lds2[base + 1]);
            float2 f10 = __half22float2(lds2[base + W]);
            float2 f11 = __half22float2(lds2[base + W + 1]);
            p0[l] = (wab.x * f00.x + wab.y * f01.x)
                  + (wcd.x * f10.x + wcd.y * f11.x);
            p1[l] = (wab.x * f00.y + wab.y * f01.y)
                  + (wcd.x * f10.y + wcd.y * f11.y);
        }
        float a0 = (p0[0] + p0[1]) + (p0[2] + p0[3]);
        float a1 = (p1[0] + p1[1]) + (p1[2] + p1[3]);

        pout[outn] = __floats2half2_rn(a0, a1);

        i = ii;
        m0 = t0; m1 = t1; cb = tb;
    }
}

// ---------------------------------------------------------------------------
// Kernel 2 (legacy, non-compacted): unchanged fallback.
// ---------------------------------------------------------------------------
template<bool PART>
__global__ __launch_bounds__(1024) void gather_t(
    const float* __restrict__ f0, const float* __restrict__ f1,
    const float* __restrict__ f2, const float* __restrict__ f3,
    const uint4* __restrict__ meta_w, const int4* __restrict__ meta_b,
    __half2* __restrict__ part2, float* __restrict__ agg)
{
    __shared__ __half2 lds2[HWT];   // 59840 B

    const int tid = threadIdx.x;
    const int bid = blockIdx.x;
    const int slice = bid & 127;         // E/2 = 128 slices
    const int c = (bid >> 7) % C_;
    const int b = bid / (128 * C_);
    const int e0 = slice * 2;

    const float* fs[4] = {f0, f1, f2, f3};

#pragma unroll
    for (int l = 0; l < L_; l++) {
        const int HW = HWH[l] * HWW[l];
        const float* s0 = fs[l] + (size_t)((b * C_ + c) * E_ + e0) * HW;
        const float* s1 = s0 + HW;
        const int quarter = HW >> 2;
        for (int q = tid; q < quarter; q += 1024) {
            int p = q * 4;
            float4 v0 = *(const float4*)(s0 + p);
            float4 v1 = *(const float4*)(s1 + p);
            union { uint4 u; __half2 h[4]; } pk;
            pk.h[0] = __floats2half2_rn(v0.x, v1.x);
            pk.h[1] = __floats2half2_rn(v0.y, v1.y);
            pk.h[2] = __floats2half2_rn(v0.z, v1.z);
            pk.h[3] = __floats2half2_rn(v0.w, v1.w);
            *(uint4*)&lds2[LOFF[l] + p] = pk.u;
        }
    }
    __syncthreads();

    const size_t mbase = (size_t)(b * C_ + c) * N_;
    const uint4* mwp = meta_w + mbase * 2;
    const int4* mbp = meta_b + mbase;
    __half2* pout = part2 + ((size_t)(b * C_ + c) * SL2_ + slice) * N_;
    float* aggb = agg + (size_t)b * N_ * E_ + e0;

    int n = tid;
    uint4 m0, m1; int4 px;
    {
        m0 = mwp[(size_t)n * 2];
        m1 = mwp[(size_t)n * 2 + 1];
        px = mbp[n];
    }

    while (n < N_) {
        int nn = n + 1024;
        uint4 t0, t1; int4 px2;
        if (nn < N_) {
            t0 = mwp[(size_t)nn * 2];
            t1 = mwp[(size_t)nn * 2 + 1];
            px2 = mbp[nn];
        }

        union { uint4 u; __half2 h[4]; } a0u, a1u;
        a0u.u = m0; a1u.u = m1;
        float4 ws[4];
        {
            float2 p0 = __half22float2(a0u.h[0]), p1 = __half22float2(a0u.h[1]);
            float2 p2 = __half22float2(a0u.h[2]), p3 = __half22float2(a0u.h[3]);
            ws[0] = make_float4(p0.x, p0.y, p1.x, p1.y);
            ws[1] = make_float4(p2.x, p2.y, p3.x, p3.y);
            float2 p4 = __half22float2(a1u.h[0]), p5 = __half22float2(a1u.h[1]);
            float2 p6 = __half22float2(a1u.h[2]), p7 = __half22float2(a1u.h[3]);
            ws[2] = make_float4(p4.x, p4.y, p5.x, p5.y);
            ws[3] = make_float4(p6.x, p6.y, p7.x, p7.y);
        }
        const int pxs[4] = {px.x, px.y, px.z, px.w};

        float a0 = 0.f, a1 = 0.f;
#pragma unroll
        for (int l = 0; l < L_; l++) {
            float4 w = ws[l];
            if (w.x != 0.f || w.y != 0.f || w.z != 0.f || w.w != 0.f) {
                const int W = HWW[l];
                const int base = LOFF[l] + pxs[l];
                float2 f00 = __half22float2(lds2[base]);
                float2 f01 = __half22float2(lds2[base + 1]);
                float2 f10 = __half22float2(lds2[base + W]);
                float2 f11 = __half22float2(lds2[base + W + 1]);
                a0 += w.x * f00.x + w.y * f01.x + w.z * f10.x + w.w * f11.x;
                a1 += w.x * f00.y + w.y * f01.y + w.z * f10.y + w.w * f11.y;
            }
        }

        if (PART) {
            pout[n] = __floats2half2_rn(a0, a1);   // coalesced 4 B store
        } else {
            if (a0 != 0.f || a1 != 0.f) {
                float* dst = aggb + (size_t)n * E_;
                atomicAdd(dst + 0, a0);
                atomicAdd(dst + 1, a1);
            }
        }

        n = nn;
        m0 = t0; m1 = t1; px = px2;
    }
}

// ---------------------------------------------------------------------------
// Kernel 3 (main path): MFMA f16 epilogue. (unchanged)
// ---------------------------------------------------------------------------
#define SAS2 264   // sA/sT row stride (halves)
#define WSS2 72    // wS row stride (halves)
#define KC 64      // k-chunk

__global__ __launch_bounds__(256) void gemm_mfma(
    const float* __restrict__ inst,
    const float* __restrict__ vp_w, const float* __restrict__ vp_b,
    const float* __restrict__ op_w, const float* __restrict__ op_b,
    const __half2* __restrict__ part2, float* __restrict__ out)
{
    __shared__ _Float16 sA[32 * SAS2];   // 16896 B
    __shared__ _Float16 sT[32 * SAS2];   // 16896 B
    __shared__ _Float16 wS[256 * WSS2];  // 36864 B

    const int tid = threadIdx.x;
    const int wave = tid >> 6;
    const int lane = tid & 63;
    const int mt = wave & 1;        // m-tile (16 points)
    const int nh = wave >> 1;       // col half (128 e)
    const int q = lane >> 4;        // quad
    const int col = lane & 15;

    const int p0 = blockIdx.x * 32;
    const int b = p0 / N_;                   // tile never crosses b
    const int nbase = p0 - b * N_;

    // ---- stage sA: reduce 6 cam partials (2-ch slices), f32 acc -> f16 ----
    {
        const int p = tid & 31, sg = tid >> 5;   // 8 slice-groups
        const int n = nbase + p;
        for (int s = sg; s < SL2_; s += 8) {
            float a0 = 0.f, a1 = 0.f;
#pragma unroll
            for (int c = 0; c < C_; c++) {
                float2 f = __half22float2(
                    part2[((size_t)(b * C_ + c) * SL2_ + s) * N_ + n]);
                a0 += f.x; a1 += f.y;
            }
            sA[p * SAS2 + s * 2 + 0] = (_Float16)a0;
            sA[p * SAS2 + s * 2 + 1] = (_Float16)a1;
        }
    }

    floatx4 acc[8];
#pragma unroll
    for (int nt = 0; nt < 8; nt++) acc[nt] = (floatx4)(0.f);

    // ---- GEMM1: tmp = agg @ vp_w^T ----
    for (int kc = 0; kc < 256 / KC; kc++) {
        __syncthreads();
        {   // stage vp_w chunk: thread = one e-row, 64 k f32 -> f16
            const float* src = vp_w + (size_t)tid * 256 + kc * KC;
            _Float16* dst = &wS[tid * WSS2];
#pragma unroll
            for (int i = 0; i < 8; i++) {
                float4 v = *(const float4*)(src + i * 8);
                float4 u = *(const float4*)(src + i * 8 + 4);
                half8 h = {(_Float16)v.x, (_Float16)v.y, (_Float16)v.z, (_Float16)v.w,
                           (_Float16)u.x, (_Float16)u.y, (_Float16)u.z, (_Float16)u.w};
                *(half8*)(dst + i * 8) = h;
            }
        }
        __syncthreads();
#pragma unroll
        for (int ks = 0; ks < KC / 32; ks++) {
            half8 a = *(half8*)&sA[(mt * 16 + col) * SAS2 + kc * KC + ks * 32 + q * 8];
#pragma unroll
            for (int nt = 0; nt < 8; nt++) {
                half8 bf = *(half8*)&wS[(nh * 128 + nt * 16 + col) * WSS2 + ks * 32 + q * 8];
                acc[nt] = __builtin_amdgcn_mfma_f32_16x16x32_f16(a, bf, acc[nt], 0, 0, 0);
            }
        }
    }

    // ---- middle: tmp = acc + vp_b + inst -> sT (f16); reset acc ----
#pragma unroll
    for (int nt = 0; nt < 8; nt++) {
        const int e = nh * 128 + nt * 16 + col;
        const float bv = vp_b[e];
#pragma unroll
        for (int r = 0; r < 4; r++) {
            const int p = mt * 16 + q * 4 + r;
            float t = acc[nt][r] + bv + inst[(size_t)(p0 + p) * E_ + e];
            sT[p * SAS2 + e] = (_Float16)t;
        }
        acc[nt] = (floatx4)(0.f);
    }

    // ---- GEMM2: out = tmp @ op_w^T ----
    for (int kc = 0; kc < 256 / KC; kc++) {
        __syncthreads();
        {
            const float* src = op_w + (size_t)tid * 256 + kc * KC;
            _Float16* dst = &wS[tid * WSS2];
#pragma unroll
            for (int i = 0; i < 8; i++) {
                float4 v = *(const float4*)(src + i * 8);
                float4 u = *(const float4*)(src + i * 8 + 4);
                half8 h = {(_Float16)v.x, (_Float16)v.y, (_Float16)v.z, (_Float16)v.w,
                           (_Float16)u.x, (_Float16)u.y, (_Float16)u.z, (_Float16)u.w};
                *(half8*)(dst + i * 8) = h;
            }
        }
        __syncthreads();
#pragma unroll
        for (int ks = 0; ks < KC / 32; ks++) {
            half8 a = *(half8*)&sT[(mt * 16 + col) * SAS2 + kc * KC + ks * 32 + q * 8];
#pragma unroll
            for (int nt = 0; nt < 8; nt++) {
                half8 bf = *(half8*)&wS[(nh * 128 + nt * 16 + col) * WSS2 + ks * 32 + q * 8];
                acc[nt] = __builtin_amdgcn_mfma_f32_16x16x32_f16(a, bf, acc[nt], 0, 0, 0);
            }
        }
    }

    // ---- store out + op_b ----
#pragma unroll
    for (int nt = 0; nt < 8; nt++) {
        const int e = nh * 128 + nt * 16 + col;
        const float ob = op_b[e];
#pragma unroll
        for (int r = 0; r < 4; r++) {
            const int p = mt * 16 + q * 4 + r;
            out[(size_t)(p0 + p) * E_ + e] = acc[nt][r] + ob;
        }
    }
}

// ---------------------------------------------------------------------------
// Fallback VALU epilogue (atomic path, PART=false). (unchanged)
// ---------------------------------------------------------------------------
#define PT 32
#define SAS 264
#define WSS 36

__global__ __launch_bounds__(256) void gemm_valu(
    const float* __restrict__ inst,
    const float* __restrict__ vp_w, const float* __restrict__ vp_b,
    const float* __restrict__ op_w, const float* __restrict__ op_b,
    float* __restrict__ io)
{
    __shared__ __align__(16) float sA[PT * SAS];
    __shared__ __align__(16) float wS[256 * WSS];

    const int tid = threadIdx.x;
    const int eg = tid & 31;
    const int pg = tid >> 5;
    const int p0 = blockIdx.x * PT;

#pragma unroll
    for (int r = 0; r < PT; r++)
        sA[r * SAS + tid] = io[(size_t)(p0 + r) * E_ + tid];
    __syncthreads();

    float acc[4][8];
#pragma unroll
    for (int j = 0; j < 4; j++)
#pragma unroll
        for (int i = 0; i < 8; i++) acc[j][i] = 0.f;

    for (int k0 = 0; k0 < 256; k0 += 32) {
        __syncthreads();
#pragma unroll
        for (int r = 0; r < 32; r++) {
            int lin = r * 256 + tid;
            int e = lin >> 5, kk = lin & 31;
            wS[e * WSS + kk] = vp_w[(size_t)e * 256 + k0 + kk];
        }
        __syncthreads();
#pragma unroll
        for (int kk = 0; kk < 32; kk += 4) {
            float4 wv4[8], av4[4];
#pragma unroll
            for (int i = 0; i < 8; i++)
                wv4[i] = *(const float4*)&wS[(eg + 32 * i) * WSS + kk];
#pragma unroll
            for (int j = 0; j < 4; j++)
                av4[j] = *(const float4*)&sA[(pg * 4 + j) * SAS + k0 + kk];
#pragma unroll
            for (int j = 0; j < 4; j++)
#pragma unroll
                for (int i = 0; i < 8; i++)
                    acc[j][i] += av4[j].x * wv4[i].x + av4[j].y * wv4[i].y
                               + av4[j].z * wv4[i].z + av4[j].w * wv4[i].w;
        }
    }

    __syncthreads();
#pragma unroll
    for (int j = 0; j < 4; j++) {
        int p = pg * 4 + j;
#pragma unroll
        for (int i = 0; i < 8; i++) {
            int e = eg + 32 * i;
            float t = acc[j][i] + vp_b[e] + inst[(size_t)(p0 + p) * E_ + e];
            sA[p * SAS + e] = t;
            acc[j][i] = 0.f;
        }
    }

    for (int k0 = 0; k0 < 256; k0 += 32) {
        __syncthreads();
#pragma unroll
        for (int r = 0; r < 32; r++) {
            int lin = r * 256 + tid;
            int e = lin >> 5, kk = lin & 31;
            wS[e * WSS + kk] = op_w[(size_t)e * 256 + k0 + kk];
        }
        __syncthreads();
#pragma unroll
        for (int kk = 0; kk < 32; kk += 4) {
            float4 wv4[8], av4[4];
#pragma unroll
            for (int i = 0; i < 8; i++)
                wv4[i] = *(const float4*)&wS[(eg + 32 * i) * WSS + kk];
#pragma unroll
            for (int j = 0; j < 4; j++)
                av4[j] = *(const float4*)&sA[(pg * 4 + j) * SAS + k0 + kk];
#pragma unroll
            for (int j = 0; j < 4; j++)
#pragma unroll
                for (int i = 0; i < 8; i++)
                    acc[j][i] += av4[j].x * wv4[i].x + av4[j].y * wv4[i].y
                               + av4[j].z * wv4[i].z + av4[j].w * wv4[i].w;
        }
    }

#pragma unroll
    for (int j = 0; j < 4; j++) {
        int p = pg * 4 + j;
#pragma unroll
        for (int i = 0; i < 8; i++) {
            int e = eg + 32 * i;
            io[(size_t)(p0 + p) * E_ + e] = acc[j][i] + op_b[e];
        }
    }
}

// ---------------------------------------------------------------------------
extern "C" void kernel_launch(void* const* d_in, const int* in_sizes, int n_in,
                              void* d_out, int out_size, void* d_ws, size_t ws_size,
                              hipStream_t stream)
{
    const float* inst   = (const float*)d_in[0];
    const float* anchor = (const float*)d_in[1];
    const float* proj   = (const float*)d_in[2];
    const float* f0     = (const float*)d_in[3];
    const float* f1     = (const float*)d_in[4];
    const float* f2     = (const float*)d_in[5];
    const float* f3     = (const float*)d_in[6];
    const float* attn_w = (const float*)d_in[7];
    const float* attn_b = (const float*)d_in[8];
    const float* vp_w   = (const float*)d_in[9];
    const float* vp_b   = (const float*)d_in[10];
    const float* op_w   = (const float*)d_in[11];
    const float* op_b   = (const float*)d_in[12];
    float* out = (float*)d_out;

    // ws layout: meta_w (32 B/pt) | meta_b (16 B/pt) | partials (fp16, 39 MB)
    //            | cmeta_w (32 B/pt) | cmeta_b (16 B/pt) | counts (12 ints)
    const size_t NPT = (size_t)B_ * C_ * N_;
    uint4* meta_w = (uint4*)d_ws;
    int4* meta_b = (int4*)((char*)d_ws + NPT * 32);
    __half2* part2 = (__half2*)((char*)d_ws + NPT * 48);
    const size_t part2_bytes = (size_t)B_ * C_ * SL2_ * N_ * sizeof(__half2);
    const size_t need = NPT * 48 + part2_bytes;
    uint4* cmeta_w = (uint4*)((char*)d_ws + need);
    int4* cmeta_b = (int4*)((char*)d_ws + need + NPT * 32);
    int* counts = (int*)((char*)d_ws + need + NPT * 48);
    const size_t need_cmp = need + NPT * 48 + 256;

    prep_kernel<<<(B_ * N_) / 256, 256, 0, stream>>>(
        inst, anchor, proj, attn_w, attn_b, meta_w, meta_b);

    if (ws_size >= need_cmp) {
        compact_kernel<<<B_ * C_, 1024, 0, stream>>>(
            meta_w, meta_b, cmeta_w, cmeta_b, counts);
        gather_compact<<<B_ * C_ * SL2_, 1024, 0, stream>>>(
            f0, f1, f2, f3, cmeta_w, cmeta_b, counts, part2);
        gemm_mfma<<<(B_ * N_) / 32, 256, 0, stream>>>(
            inst, vp_w, vp_b, op_w, op_b, part2, out);
    } else if (ws_size >= need) {
        gather_t<true><<<B_ * C_ * SL2_, 1024, 0, stream>>>(
            f0, f1, f2, f3, meta_w, meta_b, part2, out);
        gemm_mfma<<<(B_ * N_) / 32, 256, 0, stream>>>(
            inst, vp_w, vp_b, op_w, op_b, part2, out);
    } else {
        hipMemsetAsync(d_out, 0, (size_t)out_size * sizeof(float), stream);
        gather_t<false><<<B_ * C_ * SL2_, 1024, 0, stream>>>(
            f0, f1, f2, f3, meta_w, meta_b, part2, out);
        gemm_valu<<<(B_ * N_) / PT, 256, 0, stream>>>(
            inst, vp_w, vp_b, op_w, op_b, out);
    }
}

// Round 4
// 362.416 us; speedup vs baseline: 1.0009x; 1.0009x over previous
//
#include <hip/hip_runtime.h>
#include <hip/hip_fp16.h>
#include <math.h>

#define B_ 2
#define N_ 6400
#define E_ 256
#define C_ 6
#define L_ 4
#define SL2_ 128  // 2-channel slices (E/2)

// Level geometry (H, W), flattened per-channel offsets, total pixels/channel
__device__ __host__ constexpr int HWH[4] = {64, 32, 16, 8};
__device__ __host__ constexpr int HWW[4] = {176, 88, 44, 22};
__device__ __host__ constexpr int LOFF[4] = {0, 11264, 14080, 14784};
#define HWT 14960

struct __align__(8) H4 { __half2 lo, hi; };   // 4 fp16 values

typedef __attribute__((ext_vector_type(8))) _Float16 half8;
typedef __attribute__((ext_vector_type(4))) _Float16 half4;
typedef __attribute__((ext_vector_type(4))) float floatx4;

// ---------------------------------------------------------------------------
// Kernel 1: per-point prep. (unchanged)
// ---------------------------------------------------------------------------
__global__ __launch_bounds__(256) void prep_kernel(
    const float* __restrict__ inst, const float* __restrict__ anchor,
    const float* __restrict__ proj, const float* __restrict__ attn_w,
    const float* __restrict__ attn_b,
    uint4* __restrict__ meta_w, int4* __restrict__ meta_b)
{
    __shared__ float AWT[256 * 24];   // attn_w transposed [k][j]
    __shared__ float ts[256 * 33];    // inst tile [point][k-chunk], padded

    const int tid = threadIdx.x;

    for (int idx = tid; idx < 24 * 256; idx += 256) {
        int j = idx >> 8, k = idx & 255;
        AWT[k * 24 + j] = attn_w[idx];
    }
    __syncthreads();

    const int pt0 = blockIdx.x * 256;

    float acc[24];
#pragma unroll
    for (int j = 0; j < 24; j++) acc[j] = attn_b[j];

    for (int k0 = 0; k0 < 256; k0 += 32) {
#pragma unroll
        for (int r = 0; r < 32; r++) {
            int lin = r * 256 + tid;
            int p = lin >> 5, kk = lin & 31;
            ts[p * 33 + kk] = inst[(size_t)(pt0 + p) * 256 + k0 + kk];
        }
        __syncthreads();
#pragma unroll
        for (int kk = 0; kk < 32; kk++) {
            float v = ts[tid * 33 + kk];
            const float* aw = &AWT[(k0 + kk) * 24];
#pragma unroll
            for (int j = 0; j < 24; j++) acc[j] += v * aw[j];
        }
        __syncthreads();
    }

    const int pt = pt0 + tid;
    const int b = pt / N_;   // uniform per block (6400 % 256 == 0)
    const int n = pt - b * N_;

    float attn[24];
#pragma unroll
    for (int c = 0; c < C_; c++) {
        float m = fmaxf(fmaxf(acc[c * 4], acc[c * 4 + 1]),
                        fmaxf(acc[c * 4 + 2], acc[c * 4 + 3]));
        float s = 0.f;
#pragma unroll
        for (int l = 0; l < L_; l++) {
            float e = expf(acc[c * 4 + l] - m);
            attn[c * 4 + l] = e;
            s += e;
        }
        float r = 1.f / s;
#pragma unroll
        for (int l = 0; l < L_; l++) attn[c * 4 + l] *= r;
    }

    float ax = anchor[(size_t)pt * 11 + 0];
    float ay = anchor[(size_t)pt * 11 + 1];
    float az = anchor[(size_t)pt * 11 + 2];
    float wxp = (1.f / (1.f + expf(-ax))) * 102.4f - 51.2f;
    float wyp = (1.f / (1.f + expf(-ay))) * 102.4f - 51.2f;
    float wzp = (1.f / (1.f + expf(-az))) * 8.f - 5.f;

#pragma unroll
    for (int c = 0; c < C_; c++) {
        const float* P = &proj[(size_t)(b * C_ + c) * 16];
        float cx = P[0] * wxp + P[1] * wyp + P[2] * wzp + P[3];
        float cy = P[4] * wxp + P[5] * wyp + P[6] * wzp + P[7];
        float cz = P[8] * wxp + P[9] * wyp + P[10] * wzp + P[11];
        float d = fmaxf(cz, 1e-4f);
        float u = cx / d, v = cy / d;

        float x0f = floorf(u), y0f = floorf(v);
        float fx1 = u - x0f, fy1 = v - y0f;
        float fx0 = 1.f - fx1, fy0 = 1.f - fy1;

        float4 wl[4]; int bsx[4];
#pragma unroll
        for (int l = 0; l < L_; l++) {
            const int W = HWW[l], H = HWH[l];
            float ax0, ax1; int bx;
            int ix = (int)fminf(fmaxf(x0f, -2.f), (float)W);
            if (ix <= -2 || ix >= W)      { ax0 = 0.f;  ax1 = 0.f;  bx = 0; }
            else if (ix == -1)            { ax0 = fx1;  ax1 = 0.f;  bx = 0; }
            else if (ix == W - 1)         { ax0 = 0.f;  ax1 = fx0;  bx = W - 2; }
            else                          { ax0 = fx0;  ax1 = fx1;  bx = ix; }
            float ay0, ay1; int by;
            int iy = (int)fminf(fmaxf(y0f, -2.f), (float)H);
            if (iy <= -2 || iy >= H)      { ay0 = 0.f;  ay1 = 0.f;  by = 0; }
            else if (iy == -1)            { ay0 = fy1;  ay1 = 0.f;  by = 0; }
            else if (iy == H - 1)         { ay0 = 0.f;  ay1 = fy0;  by = H - 2; }
            else                          { ay0 = fy0;  ay1 = fy1;  by = iy; }

            float a = attn[c * 4 + l];
            wl[l] = make_float4(a * ay0 * ax0, a * ay0 * ax1,
                                a * ay1 * ax0, a * ay1 * ax1);
            bsx[l] = by * W + bx;
        }
        size_t mi = (size_t)(b * C_ + c) * N_ + n;
        union { uint4 u; __half2 h[4]; } q0, q1;
        q0.h[0] = __floats2half2_rn(wl[0].x, wl[0].y);
        q0.h[1] = __floats2half2_rn(wl[0].z, wl[0].w);
        q0.h[2] = __floats2half2_rn(wl[1].x, wl[1].y);
        q0.h[3] = __floats2half2_rn(wl[1].z, wl[1].w);
        q1.h[0] = __floats2half2_rn(wl[2].x, wl[2].y);
        q1.h[1] = __floats2half2_rn(wl[2].z, wl[2].w);
        q1.h[2] = __floats2half2_rn(wl[3].x, wl[3].y);
        q1.h[3] = __floats2half2_rn(wl[3].z, wl[3].w);
        meta_w[mi * 2 + 0] = q0.u;
        meta_w[mi * 2 + 1] = q1.u;
        meta_b[mi] = make_int4(bsx[0], bsx[1], bsx[2], bsx[3]);
    }
}

// ---------------------------------------------------------------------------
// Kernel 1.5: visibility compaction, OUT OF PLACE (value-idempotent across
// launches). One block per (b,c) segment; keeps entries with any nonzero
// fp16 weight. Compacted cmeta_b: {bsx0|bsx1<<16, bsx2|bsx3<<16, orig_n, 0}.
// ---------------------------------------------------------------------------
__global__ __launch_bounds__(1024) void compact_kernel(
    const uint4* __restrict__ meta_w, const int4* __restrict__ meta_b,
    uint4* __restrict__ cmeta_w, int4* __restrict__ cmeta_b,
    int* __restrict__ counts)
{
    const int seg = blockIdx.x;               // b*C + c, 0..11
    const size_t base = (size_t)seg * N_;
    __shared__ int wsum[17];

    const int tid = threadIdx.x;
    const int lane = tid & 63;
    const int wv = tid >> 6;

    int running = 0;
    for (int c0 = 0; c0 < N_; c0 += 1024) {
        const int n = c0 + tid;
        const bool valid = n < N_;
        uint4 m0 = make_uint4(0, 0, 0, 0), m1 = make_uint4(0, 0, 0, 0);
        int4 bx = make_int4(0, 0, 0, 0);
        if (valid) {
            m0 = meta_w[(base + n) * 2];
            m1 = meta_w[(base + n) * 2 + 1];
            bx = meta_b[base + n];
        }
        const bool vis = valid &&
            ((m0.x | m0.y | m0.z | m0.w | m1.x | m1.y | m1.z | m1.w) != 0u);

        unsigned long long ball = __ballot(vis);
        int wpre = __popcll(ball & ((1ull << lane) - 1ull));
        if (lane == 0) wsum[wv] = __popcll(ball);
        __syncthreads();
        if (tid == 0) {
            int r = 0;
#pragma unroll
            for (int w = 0; w < 16; w++) { int t = wsum[w]; wsum[w] = r; r += t; }
            wsum[16] = r;
        }
        __syncthreads();
        const int pos = running + wsum[wv] + wpre;
        const int ctot = wsum[16];

        if (vis) {
            cmeta_w[(base + pos) * 2]     = m0;
            cmeta_w[(base + pos) * 2 + 1] = m1;
            cmeta_b[base + pos] = make_int4(bx.x | (bx.y << 16),
                                            bx.z | (bx.w << 16), n, 0);
        }
        running += ctot;
        __syncthreads();   // wsum reused next chunk
    }
    if (tid == 0) counts[seg] = running;
}

// ---------------------------------------------------------------------------
// Kernel 2 (compacted main path): gather over visible points only.
// XCD-chunked blockIdx swizzle: hardware round-robins consecutive blockIdx
// across the 8 XCDs; remap bid=(bid%8)*192+bid/8 so each XCD owns 192
// consecutive logical blocks = 1.5 (b,c) segments -> that segment's meta
// (288 KB) stays L2-resident instead of being re-streamed from L3 by all
// 128 slice-blocks (cuts ~440 MB of L3->L2 traffic; meta latency L2-hit).
// Meta loads use a depth-2 prefetch pipeline (2 point-iterations in flight).
// ---------------------------------------------------------------------------
__global__ __launch_bounds__(1024) void gather_compact(
    const float* __restrict__ f0, const float* __restrict__ f1,
    const float* __restrict__ f2, const float* __restrict__ f3,
    const uint4* __restrict__ cmeta_w, const int4* __restrict__ cmeta_b,
    const int* __restrict__ counts, __half2* __restrict__ part2)
{
    __shared__ __half2 lds2[HWT];   // 59840 B

    const int tid = threadIdx.x;
    int bid = blockIdx.x;
    bid = (bid & 7) * 192 + (bid >> 3);   // XCD chunking (grid = 1536 = 8*192)
    const int slice = bid & 127;          // E/2 = 128 slices
    const int c = (bid >> 7) % C_;
    const int b = bid / (128 * C_);
    const int e0 = slice * 2;
    const int bc = b * C_ + c;

    __half2* pout = part2 + ((size_t)bc * SL2_ + slice) * N_;

    // zero own slice: 6400 * 4 B = 1600 uint4 stores (16B-aligned)
    for (int z = tid; z < 1600; z += 1024)
        ((uint4*)pout)[z] = make_uint4(0, 0, 0, 0);

    const float* fs[4] = {f0, f1, f2, f3};

#pragma unroll
    for (int l = 0; l < L_; l++) {
        const int HW = HWH[l] * HWW[l];
        const float* s0 = fs[l] + (size_t)(bc * E_ + e0) * HW;
        const float* s1 = s0 + HW;
        const int quarter = HW >> 2;
        for (int q = tid; q < quarter; q += 1024) {
            int p = q * 4;
            float4 v0 = *(const float4*)(s0 + p);
            float4 v1 = *(const float4*)(s1 + p);
            union { uint4 u; __half2 h[4]; } pk;
            pk.h[0] = __floats2half2_rn(v0.x, v1.x);
            pk.h[1] = __floats2half2_rn(v0.y, v1.y);
            pk.h[2] = __floats2half2_rn(v0.z, v1.z);
            pk.h[3] = __floats2half2_rn(v0.w, v1.w);
            *(uint4*)&lds2[LOFF[l] + p] = pk.u;
        }
    }
    __syncthreads();

    const int nvis = counts[bc];
    const uint4* mwp = cmeta_w + (size_t)bc * N_ * 2;
    const int4* mbp = cmeta_b + (size_t)bc * N_;

    int i = tid;
    uint4 m0, m1; int4 cb;       // current
    uint4 n0, n1; int4 nb;       // next (i+1024)
    if (i < nvis) {
        m0 = mwp[(size_t)i * 2];
        m1 = mwp[(size_t)i * 2 + 1];
        cb = mbp[i];
    }
    if (i + 1024 < nvis) {
        n0 = mwp[(size_t)(i + 1024) * 2];
        n1 = mwp[(size_t)(i + 1024) * 2 + 1];
        nb = mbp[i + 1024];
    }

    while (i < nvis) {
        const int i2 = i + 2048;
        uint4 t0, t1; int4 tb;
        if (i2 < nvis) {
            t0 = mwp[(size_t)i2 * 2];
            t1 = mwp[(size_t)i2 * 2 + 1];
            tb = mbp[i2];
        }

        union { uint4 u; __half2 h[4]; } a0u, a1u;
        a0u.u = m0; a1u.u = m1;
        __half2 wh[8];
        wh[0] = a0u.h[0]; wh[1] = a0u.h[1]; wh[2] = a0u.h[2]; wh[3] = a0u.h[3];
        wh[4] = a1u.h[0]; wh[5] = a1u.h[1]; wh[6] = a1u.h[2]; wh[7] = a1u.h[3];

        int bs[4];
        bs[0] = cb.x & 0xffff;
        bs[1] = ((unsigned)cb.x) >> 16;
        bs[2] = cb.y & 0xffff;
        bs[3] = ((unsigned)cb.y) >> 16;
        const int outn = cb.z;

        float p0[4], p1[4];
#pragma unroll
        for (int l = 0; l < L_; l++) {
            const int W = HWW[l];
            const int base = LOFF[l] + bs[l];
            float2 wab = __half22float2(wh[l * 2]);      // w00, w01
            float2 wcd = __half22float2(wh[l * 2 + 1]);  // w10, w11
            float2 f00 = __half22float2(lds2[base]);
            float2 f01 = __half22float2(lds2[base + 1]);
            float2 f10 = __half22float2(lds2[base + W]);
            float2 f11 = __half22float2(lds2[base + W + 1]);
            p0[l] = (wab.x * f00.x + wab.y * f01.x)
                  + (wcd.x * f10.x + wcd.y * f11.x);
            p1[l] = (wab.x * f00.y + wab.y * f01.y)
                  + (wcd.x * f10.y + wcd.y * f11.y);
        }
        float a0 = (p0[0] + p0[1]) + (p0[2] + p0[3]);
        float a1 = (p1[0] + p1[1]) + (p1[2] + p1[3]);

        pout[outn] = __floats2half2_rn(a0, a1);

        i += 1024;
        m0 = n0; m1 = n1; cb = nb;
        n0 = t0; n1 = t1; nb = tb;
    }
}

// ---------------------------------------------------------------------------
// Kernel 2 (legacy, non-compacted): unchanged fallback.
// ---------------------------------------------------------------------------
template<bool PART>
__global__ __launch_bounds__(1024) void gather_t(
    const float* __restrict__ f0, const float* __restrict__ f1,
    const float* __restrict__ f2, const float* __restrict__ f3,
    const uint4* __restrict__ meta_w, const int4* __restrict__ meta_b,
    __half2* __restrict__ part2, float* __restrict__ agg)
{
    __shared__ __half2 lds2[HWT];   // 59840 B

    const int tid = threadIdx.x;
    const int bid = blockIdx.x;
    const int slice = bid & 127;         // E/2 = 128 slices
    const int c = (bid >> 7) % C_;
    const int b = bid / (128 * C_);
    const int e0 = slice * 2;

    const float* fs[4] = {f0, f1, f2, f3};

#pragma unroll
    for (int l = 0; l < L_; l++) {
        const int HW = HWH[l] * HWW[l];
        const float* s0 = fs[l] + (size_t)((b * C_ + c) * E_ + e0) * HW;
        const float* s1 = s0 + HW;
        const int quarter = HW >> 2;
        for (int q = tid; q < quarter; q += 1024) {
            int p = q * 4;
            float4 v0 = *(const float4*)(s0 + p);
            float4 v1 = *(const float4*)(s1 + p);
            union { uint4 u; __half2 h[4]; } pk;
            pk.h[0] = __floats2half2_rn(v0.x, v1.x);
            pk.h[1] = __floats2half2_rn(v0.y, v1.y);
            pk.h[2] = __floats2half2_rn(v0.z, v1.z);
            pk.h[3] = __floats2half2_rn(v0.w, v1.w);
            *(uint4*)&lds2[LOFF[l] + p] = pk.u;
        }
    }
    __syncthreads();

    const size_t mbase = (size_t)(b * C_ + c) * N_;
    const uint4* mwp = meta_w + mbase * 2;
    const int4* mbp = meta_b + mbase;
    __half2* pout = part2 + ((size_t)(b * C_ + c) * SL2_ + slice) * N_;
    float* aggb = agg + (size_t)b * N_ * E_ + e0;

    int n = tid;
    uint4 m0, m1; int4 px;
    {
        m0 = mwp[(size_t)n * 2];
        m1 = mwp[(size_t)n * 2 + 1];
        px = mbp[n];
    }

    while (n < N_) {
        int nn = n + 1024;
        uint4 t0, t1; int4 px2;
        if (nn < N_) {
            t0 = mwp[(size_t)nn * 2];
            t1 = mwp[(size_t)nn * 2 + 1];
            px2 = mbp[nn];
        }

        union { uint4 u; __half2 h[4]; } a0u, a1u;
        a0u.u = m0; a1u.u = m1;
        float4 ws[4];
        {
            float2 p0 = __half22float2(a0u.h[0]), p1 = __half22float2(a0u.h[1]);
            float2 p2 = __half22float2(a0u.h[2]), p3 = __half22float2(a0u.h[3]);
            ws[0] = make_float4(p0.x, p0.y, p1.x, p1.y);
            ws[1] = make_float4(p2.x, p2.y, p3.x, p3.y);
            float2 p4 = __half22float2(a1u.h[0]), p5 = __half22float2(a1u.h[1]);
            float2 p6 = __half22float2(a1u.h[2]), p7 = __half22float2(a1u.h[3]);
            ws[2] = make_float4(p4.x, p4.y, p5.x, p5.y);
            ws[3] = make_float4(p6.x, p6.y, p7.x, p7.y);
        }
        const int pxs[4] = {px.x, px.y, px.z, px.w};

        float a0 = 0.f, a1 = 0.f;
#pragma unroll
        for (int l = 0; l < L_; l++) {
            float4 w = ws[l];
            if (w.x != 0.f || w.y != 0.f || w.z != 0.f || w.w != 0.f) {
                const int W = HWW[l];
                const int base = LOFF[l] + pxs[l];
                float2 f00 = __half22float2(lds2[base]);
                float2 f01 = __half22float2(lds2[base + 1]);
                float2 f10 = __half22float2(lds2[base + W]);
                float2 f11 = __half22float2(lds2[base + W + 1]);
                a0 += w.x * f00.x + w.y * f01.x + w.z * f10.x + w.w * f11.x;
                a1 += w.x * f00.y + w.y * f01.y + w.z * f10.y + w.w * f11.y;
            }
        }

        if (PART) {
            pout[n] = __floats2half2_rn(a0, a1);   // coalesced 4 B store
        } else {
            if (a0 != 0.f || a1 != 0.f) {
                float* dst = aggb + (size_t)n * E_;
                atomicAdd(dst + 0, a0);
                atomicAdd(dst + 1, a1);
            }
        }

        n = nn;
        m0 = t0; m1 = t1; px = px2;
    }
}

// ---------------------------------------------------------------------------
// Kernel 3 (main path): MFMA f16 epilogue. (unchanged)
// ---------------------------------------------------------------------------
#define SAS2 264   // sA/sT row stride (halves)
#define WSS2 72    // wS row stride (halves)
#define KC 64      // k-chunk

__global__ __launch_bounds__(256) void gemm_mfma(
    const float* __restrict__ inst,
    const float* __restrict__ vp_w, const float* __restrict__ vp_b,
    const float* __restrict__ op_w, const float* __restrict__ op_b,
    const __half2* __restrict__ part2, float* __restrict__ out)
{
    __shared__ _Float16 sA[32 * SAS2];   // 16896 B
    __shared__ _Float16 sT[32 * SAS2];   // 16896 B
    __shared__ _Float16 wS[256 * WSS2];  // 36864 B

    const int tid = threadIdx.x;
    const int wave = tid >> 6;
    const int lane = tid & 63;
    const int mt = wave & 1;        // m-tile (16 points)
    const int nh = wave >> 1;       // col half (128 e)
    const int q = lane >> 4;        // quad
    const int col = lane & 15;

    const int p0 = blockIdx.x * 32;
    const int b = p0 / N_;                   // tile never crosses b
    const int nbase = p0 - b * N_;

    // ---- stage sA: reduce 6 cam partials (2-ch slices), f32 acc -> f16 ----
    {
        const int p = tid & 31, sg = tid >> 5;   // 8 slice-groups
        const int n = nbase + p;
        for (int s = sg; s < SL2_; s += 8) {
            float a0 = 0.f, a1 = 0.f;
#pragma unroll
            for (int c = 0; c < C_; c++) {
                float2 f = __half22float2(
                    part2[((size_t)(b * C_ + c) * SL2_ + s) * N_ + n]);
                a0 += f.x; a1 += f.y;
            }
            sA[p * SAS2 + s * 2 + 0] = (_Float16)a0;
            sA[p * SAS2 + s * 2 + 1] = (_Float16)a1;
        }
    }

    floatx4 acc[8];
#pragma unroll
    for (int nt = 0; nt < 8; nt++) acc[nt] = (floatx4)(0.f);

    // ---- GEMM1: tmp = agg @ vp_w^T ----
    for (int kc = 0; kc < 256 / KC; kc++) {
        __syncthreads();
        {   // stage vp_w chunk: thread = one e-row, 64 k f32 -> f16
            const float* src = vp_w + (size_t)tid * 256 + kc * KC;
            _Float16* dst = &wS[tid * WSS2];
#pragma unroll
            for (int i = 0; i < 8; i++) {
                float4 v = *(const float4*)(src + i * 8);
                float4 u = *(const float4*)(src + i * 8 + 4);
                half8 h = {(_Float16)v.x, (_Float16)v.y, (_Float16)v.z, (_Float16)v.w,
                           (_Float16)u.x, (_Float16)u.y, (_Float16)u.z, (_Float16)u.w};
                *(half8*)(dst + i * 8) = h;
            }
        }
        __syncthreads();
#pragma unroll
        for (int ks = 0; ks < KC / 32; ks++) {
            half8 a = *(half8*)&sA[(mt * 16 + col) * SAS2 + kc * KC + ks * 32 + q * 8];
#pragma unroll
            for (int nt = 0; nt < 8; nt++) {
                half8 bf = *(half8*)&wS[(nh * 128 + nt * 16 + col) * WSS2 + ks * 32 + q * 8];
                acc[nt] = __builtin_amdgcn_mfma_f32_16x16x32_f16(a, bf, acc[nt], 0, 0, 0);
            }
        }
    }

    // ---- middle: tmp = acc + vp_b + inst -> sT (f16); reset acc ----
#pragma unroll
    for (int nt = 0; nt < 8; nt++) {
        const int e = nh * 128 + nt * 16 + col;
        const float bv = vp_b[e];
#pragma unroll
        for (int r = 0; r < 4; r++) {
            const int p = mt * 16 + q * 4 + r;
            float t = acc[nt][r] + bv + inst[(size_t)(p0 + p) * E_ + e];
            sT[p * SAS2 + e] = (_Float16)t;
        }
        acc[nt] = (floatx4)(0.f);
    }

    // ---- GEMM2: out = tmp @ op_w^T ----
    for (int kc = 0; kc < 256 / KC; kc++) {
        __syncthreads();
        {
            const float* src = op_w + (size_t)tid * 256 + kc * KC;
            _Float16* dst = &wS[tid * WSS2];
#pragma unroll
            for (int i = 0; i < 8; i++) {
                float4 v = *(const float4*)(src + i * 8);
                float4 u = *(const float4*)(src + i * 8 + 4);
                half8 h = {(_Float16)v.x, (_Float16)v.y, (_Float16)v.z, (_Float16)v.w,
                           (_Float16)u.x, (_Float16)u.y, (_Float16)u.z, (_Float16)u.w};
                *(half8*)(dst + i * 8) = h;
            }
        }
        __syncthreads();
#pragma unroll
        for (int ks = 0; ks < KC / 32; ks++) {
            half8 a = *(half8*)&sT[(mt * 16 + col) * SAS2 + kc * KC + ks * 32 + q * 8];
#pragma unroll
            for (int nt = 0; nt < 8; nt++) {
                half8 bf = *(half8*)&wS[(nh * 128 + nt * 16 + col) * WSS2 + ks * 32 + q * 8];
                acc[nt] = __builtin_amdgcn_mfma_f32_16x16x32_f16(a, bf, acc[nt], 0, 0, 0);
            }
        }
    }

    // ---- store out + op_b ----
#pragma unroll
    for (int nt = 0; nt < 8; nt++) {
        const int e = nh * 128 + nt * 16 + col;
        const float ob = op_b[e];
#pragma unroll
        for (int r = 0; r < 4; r++) {
            const int p = mt * 16 + q * 4 + r;
            out[(size_t)(p0 + p) * E_ + e] = acc[nt][r] + ob;
        }
    }
}

// ---------------------------------------------------------------------------
// Fallback VALU epilogue (atomic path, PART=false). (unchanged)
// ---------------------------------------------------------------------------
#define PT 32
#define SAS 264
#define WSS 36

__global__ __launch_bounds__(256) void gemm_valu(
    const float* __restrict__ inst,
    const float* __restrict__ vp_w, const float* __restrict__ vp_b,
    const float* __restrict__ op_w, const float* __restrict__ op_b,
    float* __restrict__ io)
{
    __shared__ __align__(16) float sA[PT * SAS];
    __shared__ __align__(16) float wS[256 * WSS];

    const int tid = threadIdx.x;
    const int eg = tid & 31;
    const int pg = tid >> 5;
    const int p0 = blockIdx.x * PT;

#pragma unroll
    for (int r = 0; r < PT; r++)
        sA[r * SAS + tid] = io[(size_t)(p0 + r) * E_ + tid];
    __syncthreads();

    float acc[4][8];
#pragma unroll
    for (int j = 0; j < 4; j++)
#pragma unroll
        for (int i = 0; i < 8; i++) acc[j][i] = 0.f;

    for (int k0 = 0; k0 < 256; k0 += 32) {
        __syncthreads();
#pragma unroll
        for (int r = 0; r < 32; r++) {
            int lin = r * 256 + tid;
            int e = lin >> 5, kk = lin & 31;
            wS[e * WSS + kk] = vp_w[(size_t)e * 256 + k0 + kk];
        }
        __syncthreads();
#pragma unroll
        for (int kk = 0; kk < 32; kk += 4) {
            float4 wv4[8], av4[4];
#pragma unroll
            for (int i = 0; i < 8; i++)
                wv4[i] = *(const float4*)&wS[(eg + 32 * i) * WSS + kk];
#pragma unroll
            for (int j = 0; j < 4; j++)
                av4[j] = *(const float4*)&sA[(pg * 4 + j) * SAS + k0 + kk];
#pragma unroll
            for (int j = 0; j < 4; j++)
#pragma unroll
                for (int i = 0; i < 8; i++)
                    acc[j][i] += av4[j].x * wv4[i].x + av4[j].y * wv4[i].y
                               + av4[j].z * wv4[i].z + av4[j].w * wv4[i].w;
        }
    }

    __syncthreads();
#pragma unroll
    for (int j = 0; j < 4; j++) {
        int p = pg * 4 + j;
#pragma unroll
        for (int i = 0; i < 8; i++) {
            int e = eg + 32 * i;
            float t = acc[j][i] + vp_b[e] + inst[(size_t)(p0 + p) * E_ + e];
            sA[p * SAS + e] = t;
            acc[j][i] = 0.f;
        }
    }

    for (int k0 = 0; k0 < 256; k0 += 32) {
        __syncthreads();
#pragma unroll
        for (int r = 0; r < 32; r++) {
            int lin = r * 256 + tid;
            int e = lin >> 5, kk = lin & 31;
            wS[e * WSS + kk] = op_w[(size_t)e * 256 + k0 + kk];
        }
        __syncthreads();
#pragma unroll
        for (int kk = 0; kk < 32; kk += 4) {
            float4 wv4[8], av4[4];
#pragma unroll
            for (int i = 0; i < 8; i++)
                wv4[i] = *(const float4*)&wS[(eg + 32 * i) * WSS + kk];
#pragma unroll
            for (int j = 0; j < 4; j++)
                av4[j] = *(const float4*)&sA[(pg * 4 + j) * SAS + k0 + kk];
#pragma unroll
            for (int j = 0; j < 4; j++)
#pragma unroll
                for (int i = 0; i < 8; i++)
                    acc[j][i] += av4[j].x * wv4[i].x + av4[j].y * wv4[i].y
                               + av4[j].z * wv4[i].z + av4[j].w * wv4[i].w;
        }
    }

#pragma unroll
    for (int j = 0; j < 4; j++) {
        int p = pg * 4 + j;
#pragma unroll
        for (int i = 0; i < 8; i++) {
            int e = eg + 32 * i;
            io[(size_t)(p0 + p) * E_ + e] = acc[j][i] + op_b[e];
        }
    }
}

// ---------------------------------------------------------------------------
extern "C" void kernel_launch(void* const* d_in, const int* in_sizes, int n_in,
                              void* d_out, int out_size, void* d_ws, size_t ws_size,
                              hipStream_t stream)
{
    const float* inst   = (const float*)d_in[0];
    const float* anchor = (const float*)d_in[1];
    const float* proj   = (const float*)d_in[2];
    const float* f0     = (const float*)d_in[3];
    const float* f1     = (const float*)d_in[4];
    const float* f2     = (const float*)d_in[5];
    const float* f3     = (const float*)d_in[6];
    const float* attn_w = (const float*)d_in[7];
    const float* attn_b = (const float*)d_in[8];
    const float* vp_w   = (const float*)d_in[9];
    const float* vp_b   = (const float*)d_in[10];
    const float* op_w   = (const float*)d_in[11];
    const float* op_b   = (const float*)d_in[12];
    float* out = (float*)d_out;

    // ws layout: meta_w (32 B/pt) | meta_b (16 B/pt) | partials (fp16, 39 MB)
    //            | cmeta_w (32 B/pt) | cmeta_b (16 B/pt) | counts (12 ints)
    const size_t NPT = (size_t)B_ * C_ * N_;
    uint4* meta_w = (uint4*)d_ws;
    int4* meta_b = (int4*)((char*)d_ws + NPT * 32);
    __half2* part2 = (__half2*)((char*)d_ws + NPT * 48);
    const size_t part2_bytes = (size_t)B_ * C_ * SL2_ * N_ * sizeof(__half2);
    const size_t need = NPT * 48 + part2_bytes;
    uint4* cmeta_w = (uint4*)((char*)d_ws + need);
    int4* cmeta_b = (int4*)((char*)d_ws + need + NPT * 32);
    int* counts = (int*)((char*)d_ws + need + NPT * 48);
    const size_t need_cmp = need + NPT * 48 + 256;

    prep_kernel<<<(B_ * N_) / 256, 256, 0, stream>>>(
        inst, anchor, proj, attn_w, attn_b, meta_w, meta_b);

    if (ws_size >= need_cmp) {
        compact_kernel<<<B_ * C_, 1024, 0, stream>>>(
            meta_w, meta_b, cmeta_w, cmeta_b, counts);
        gather_compact<<<B_ * C_ * SL2_, 1024, 0, stream>>>(
            f0, f1, f2, f3, cmeta_w, cmeta_b, counts, part2);
        gemm_mfma<<<(B_ * N_) / 32, 256, 0, stream>>>(
            inst, vp_w, vp_b, op_w, op_b, part2, out);
    } else if (ws_size >= need) {
        gather_t<true><<<B_ * C_ * SL2_, 1024, 0, stream>>>(
            f0, f1, f2, f3, meta_w, meta_b, part2, out);
        gemm_mfma<<<(B_ * N_) / 32, 256, 0, stream>>>(
            inst, vp_w, vp_b, op_w, op_b, part2, out);
    } else {
        hipMemsetAsync(d_out, 0, (size_t)out_size * sizeof(float), stream);
        gather_t<false><<<B_ * C_ * SL2_, 1024, 0, stream>>>(
            f0, f1, f2, f3, meta_w, meta_b, part2, out);
        gemm_valu<<<(B_ * N_) / PT, 256, 0, stream>>>(
            inst, vp_w, vp_b, op_w, op_b, out);
    }
}

// Round 5
// 348.751 us; speedup vs baseline: 1.0401x; 1.0392x over previous
//
#include <hip/hip_runtime.h>
#include <hip/hip_fp16.h>
#include <math.h>

#define B_ 2
#define N_ 6400
#define E_ 256
#define C_ 6
#define L_ 4
#define SL2_ 128  // 2-channel slices (E/2)

// Level geometry (H, W), flattened per-channel offsets, total pixels/channel
__device__ __host__ constexpr int HWH[4] = {64, 32, 16, 8};
__device__ __host__ constexpr int HWW[4] = {176, 88, 44, 22};
__device__ __host__ constexpr int LOFF[4] = {0, 11264, 14080, 14784};
#define HWT 14960

typedef __attribute__((ext_vector_type(8))) _Float16 half8;
typedef __attribute__((ext_vector_type(4))) float floatx4;

// ---------------------------------------------------------------------------
// Kernel 1: per-point prep. (unchanged)
// ---------------------------------------------------------------------------
__global__ __launch_bounds__(256) void prep_kernel(
    const float* __restrict__ inst, const float* __restrict__ anchor,
    const float* __restrict__ proj, const float* __restrict__ attn_w,
    const float* __restrict__ attn_b,
    uint4* __restrict__ meta_w, int4* __restrict__ meta_b)
{
    __shared__ float AWT[256 * 24];   // attn_w transposed [k][j]
    __shared__ float ts[256 * 33];    // inst tile [point][k-chunk], padded

    const int tid = threadIdx.x;

    for (int idx = tid; idx < 24 * 256; idx += 256) {
        int j = idx >> 8, k = idx & 255;
        AWT[k * 24 + j] = attn_w[idx];
    }
    __syncthreads();

    const int pt0 = blockIdx.x * 256;

    float acc[24];
#pragma unroll
    for (int j = 0; j < 24; j++) acc[j] = attn_b[j];

    for (int k0 = 0; k0 < 256; k0 += 32) {
#pragma unroll
        for (int r = 0; r < 32; r++) {
            int lin = r * 256 + tid;
            int p = lin >> 5, kk = lin & 31;
            ts[p * 33 + kk] = inst[(size_t)(pt0 + p) * 256 + k0 + kk];
        }
        __syncthreads();
#pragma unroll
        for (int kk = 0; kk < 32; kk++) {
            float v = ts[tid * 33 + kk];
            const float* aw = &AWT[(k0 + kk) * 24];
#pragma unroll
            for (int j = 0; j < 24; j++) acc[j] += v * aw[j];
        }
        __syncthreads();
    }

    const int pt = pt0 + tid;
    const int b = pt / N_;   // uniform per block (6400 % 256 == 0)
    const int n = pt - b * N_;

    float attn[24];
#pragma unroll
    for (int c = 0; c < C_; c++) {
        float m = fmaxf(fmaxf(acc[c * 4], acc[c * 4 + 1]),
                        fmaxf(acc[c * 4 + 2], acc[c * 4 + 3]));
        float s = 0.f;
#pragma unroll
        for (int l = 0; l < L_; l++) {
            float e = expf(acc[c * 4 + l] - m);
            attn[c * 4 + l] = e;
            s += e;
        }
        float r = 1.f / s;
#pragma unroll
        for (int l = 0; l < L_; l++) attn[c * 4 + l] *= r;
    }

    float ax = anchor[(size_t)pt * 11 + 0];
    float ay = anchor[(size_t)pt * 11 + 1];
    float az = anchor[(size_t)pt * 11 + 2];
    float wxp = (1.f / (1.f + expf(-ax))) * 102.4f - 51.2f;
    float wyp = (1.f / (1.f + expf(-ay))) * 102.4f - 51.2f;
    float wzp = (1.f / (1.f + expf(-az))) * 8.f - 5.f;

#pragma unroll
    for (int c = 0; c < C_; c++) {
        const float* P = &proj[(size_t)(b * C_ + c) * 16];
        float cx = P[0] * wxp + P[1] * wyp + P[2] * wzp + P[3];
        float cy = P[4] * wxp + P[5] * wyp + P[6] * wzp + P[7];
        float cz = P[8] * wxp + P[9] * wyp + P[10] * wzp + P[11];
        float d = fmaxf(cz, 1e-4f);
        float u = cx / d, v = cy / d;

        float x0f = floorf(u), y0f = floorf(v);
        float fx1 = u - x0f, fy1 = v - y0f;
        float fx0 = 1.f - fx1, fy0 = 1.f - fy1;

        float4 wl[4]; int bsx[4];
#pragma unroll
        for (int l = 0; l < L_; l++) {
            const int W = HWW[l], H = HWH[l];
            float ax0, ax1; int bx;
            int ix = (int)fminf(fmaxf(x0f, -2.f), (float)W);
            if (ix <= -2 || ix >= W)      { ax0 = 0.f;  ax1 = 0.f;  bx = 0; }
            else if (ix == -1)            { ax0 = fx1;  ax1 = 0.f;  bx = 0; }
            else if (ix == W - 1)         { ax0 = 0.f;  ax1 = fx0;  bx = W - 2; }
            else                          { ax0 = fx0;  ax1 = fx1;  bx = ix; }
            float ay0, ay1; int by;
            int iy = (int)fminf(fmaxf(y0f, -2.f), (float)H);
            if (iy <= -2 || iy >= H)      { ay0 = 0.f;  ay1 = 0.f;  by = 0; }
            else if (iy == -1)            { ay0 = fy1;  ay1 = 0.f;  by = 0; }
            else if (iy == H - 1)         { ay0 = 0.f;  ay1 = fy0;  by = H - 2; }
            else                          { ay0 = fy0;  ay1 = fy1;  by = iy; }

            float a = attn[c * 4 + l];
            wl[l] = make_float4(a * ay0 * ax0, a * ay0 * ax1,
                                a * ay1 * ax0, a * ay1 * ax1);
            bsx[l] = by * W + bx;
        }
        size_t mi = (size_t)(b * C_ + c) * N_ + n;
        union { uint4 u; __half2 h[4]; } q0, q1;
        q0.h[0] = __floats2half2_rn(wl[0].x, wl[0].y);
        q0.h[1] = __floats2half2_rn(wl[0].z, wl[0].w);
        q0.h[2] = __floats2half2_rn(wl[1].x, wl[1].y);
        q0.h[3] = __floats2half2_rn(wl[1].z, wl[1].w);
        q1.h[0] = __floats2half2_rn(wl[2].x, wl[2].y);
        q1.h[1] = __floats2half2_rn(wl[2].z, wl[2].w);
        q1.h[2] = __floats2half2_rn(wl[3].x, wl[3].y);
        q1.h[3] = __floats2half2_rn(wl[3].z, wl[3].w);
        meta_w[mi * 2 + 0] = q0.u;
        meta_w[mi * 2 + 1] = q1.u;
        meta_b[mi] = make_int4(bsx[0], bsx[1], bsx[2], bsx[3]);
    }
}

// ---------------------------------------------------------------------------
// Kernel 2: gather, dense (store every n -> no zero-fill; write = 39 MB).
// XCD-chunked blockIdx swizzle (each XCD owns 192 consecutive logical blocks
// = 1.5 (b,c) segments -> meta L2-resident) + depth-2 meta prefetch.
// part2 layout: __half2[((b*C+c)*SL2 + slice)*N + n].
// ---------------------------------------------------------------------------
template<bool PART>
__global__ __launch_bounds__(1024) void gather_t(
    const float* __restrict__ f0, const float* __restrict__ f1,
    const float* __restrict__ f2, const float* __restrict__ f3,
    const uint4* __restrict__ meta_w, const int4* __restrict__ meta_b,
    __half2* __restrict__ part2, float* __restrict__ agg)
{
    __shared__ __half2 lds2[HWT];   // 59840 B

    const int tid = threadIdx.x;
    int bid = blockIdx.x;
    bid = (bid & 7) * 192 + (bid >> 3);   // XCD chunking (grid = 1536 = 8*192)
    const int slice = bid & 127;          // E/2 = 128 slices
    const int c = (bid >> 7) % C_;
    const int b = bid / (128 * C_);
    const int e0 = slice * 2;
    const int bc = b * C_ + c;

    const float* fs[4] = {f0, f1, f2, f3};

#pragma unroll
    for (int l = 0; l < L_; l++) {
        const int HW = HWH[l] * HWW[l];
        const float* s0 = fs[l] + (size_t)(bc * E_ + e0) * HW;
        const float* s1 = s0 + HW;
        const int quarter = HW >> 2;
        for (int q = tid; q < quarter; q += 1024) {
            int p = q * 4;
            float4 v0 = *(const float4*)(s0 + p);
            float4 v1 = *(const float4*)(s1 + p);
            union { uint4 u; __half2 h[4]; } pk;
            pk.h[0] = __floats2half2_rn(v0.x, v1.x);
            pk.h[1] = __floats2half2_rn(v0.y, v1.y);
            pk.h[2] = __floats2half2_rn(v0.z, v1.z);
            pk.h[3] = __floats2half2_rn(v0.w, v1.w);
            *(uint4*)&lds2[LOFF[l] + p] = pk.u;
        }
    }
    __syncthreads();

    const size_t mbase = (size_t)bc * N_;
    const uint4* mwp = meta_w + mbase * 2;
    const int4* mbp = meta_b + mbase;
    __half2* pout = part2 + ((size_t)bc * SL2_ + slice) * N_;
    float* aggb = agg + (size_t)b * N_ * E_ + e0;

    int n = tid;
    uint4 m0, m1; int4 px;       // current
    uint4 o0, o1; int4 ox;       // next (n+1024)
    {
        m0 = mwp[(size_t)n * 2];
        m1 = mwp[(size_t)n * 2 + 1];
        px = mbp[n];
    }
    if (n + 1024 < N_) {
        o0 = mwp[(size_t)(n + 1024) * 2];
        o1 = mwp[(size_t)(n + 1024) * 2 + 1];
        ox = mbp[n + 1024];
    }

    while (n < N_) {
        const int n2 = n + 2048;
        uint4 t0, t1; int4 tx;
        if (n2 < N_) {
            t0 = mwp[(size_t)n2 * 2];
            t1 = mwp[(size_t)n2 * 2 + 1];
            tx = mbp[n2];
        }

        union { uint4 u; __half2 h[4]; } a0u, a1u;
        a0u.u = m0; a1u.u = m1;
        float4 ws[4];
        {
            float2 p0 = __half22float2(a0u.h[0]), p1 = __half22float2(a0u.h[1]);
            float2 p2 = __half22float2(a0u.h[2]), p3 = __half22float2(a0u.h[3]);
            ws[0] = make_float4(p0.x, p0.y, p1.x, p1.y);
            ws[1] = make_float4(p2.x, p2.y, p3.x, p3.y);
            float2 p4 = __half22float2(a1u.h[0]), p5 = __half22float2(a1u.h[1]);
            float2 p6 = __half22float2(a1u.h[2]), p7 = __half22float2(a1u.h[3]);
            ws[2] = make_float4(p4.x, p4.y, p5.x, p5.y);
            ws[3] = make_float4(p6.x, p6.y, p7.x, p7.y);
        }
        const int pxs[4] = {px.x, px.y, px.z, px.w};

        float a0 = 0.f, a1 = 0.f;
#pragma unroll
        for (int l = 0; l < L_; l++) {
            float4 w = ws[l];
            if (w.x != 0.f || w.y != 0.f || w.z != 0.f || w.w != 0.f) {
                const int W = HWW[l];
                const int base = LOFF[l] + pxs[l];
                float2 f00 = __half22float2(lds2[base]);
                float2 f01 = __half22float2(lds2[base + 1]);
                float2 f10 = __half22float2(lds2[base + W]);
                float2 f11 = __half22float2(lds2[base + W + 1]);
                a0 += w.x * f00.x + w.y * f01.x + w.z * f10.x + w.w * f11.x;
                a1 += w.x * f00.y + w.y * f01.y + w.z * f10.y + w.w * f11.y;
            }
        }

        if (PART) {
            pout[n] = __floats2half2_rn(a0, a1);   // coalesced 4 B store
        } else {
            if (a0 != 0.f || a1 != 0.f) {
                float* dst = aggb + (size_t)n * E_;
                atomicAdd(dst + 0, a0);
                atomicAdd(dst + 1, a1);
            }
        }

        n += 1024;
        m0 = o0; m1 = o1; px = ox;
        o0 = t0; o1 = t1; ox = tx;
    }
}

// ---------------------------------------------------------------------------
// Kernel 3 (main path): MFMA f16 epilogue, 64-point tiles / 512 threads.
// Halves per-point weight re-staging vs the 32-pt version (weights are
// staged once per 64 points instead of once per 32). 8 waves: 4 m-tiles
// (16 pts) x 2 col-halves (128 e). LDS: sA 33 KB + sT 33 KB + wS 36 KB.
// ---------------------------------------------------------------------------
#define SAS2 264   // sA/sT row stride (halves)
#define WSS2 72    // wS row stride (halves)
#define KC 64      // k-chunk

__global__ __launch_bounds__(512) void gemm_mfma(
    const float* __restrict__ inst,
    const float* __restrict__ vp_w, const float* __restrict__ vp_b,
    const float* __restrict__ op_w, const float* __restrict__ op_b,
    const __half2* __restrict__ part2, float* __restrict__ out)
{
    __shared__ _Float16 sA[64 * SAS2];   // 33792 B
    __shared__ _Float16 sT[64 * SAS2];   // 33792 B
    __shared__ _Float16 wS[256 * WSS2];  // 36864 B

    const int tid = threadIdx.x;
    const int wave = tid >> 6;
    const int lane = tid & 63;
    const int mt = wave & 3;        // m-tile (16 points), 4 tiles
    const int nh = wave >> 2;       // col half (128 e)
    const int q = lane >> 4;        // quad
    const int col = lane & 15;

    const int p0 = blockIdx.x * 64;
    const int b = p0 / N_;                   // tile never crosses b
    const int nbase = p0 - b * N_;

    // ---- stage sA: reduce 6 cam partials (2-ch slices), f32 acc -> f16 ----
    {
        const int p = tid & 63, sg = tid >> 6;   // 8 slice-groups
        const int n = nbase + p;
        for (int s = sg; s < SL2_; s += 8) {
            float a0 = 0.f, a1 = 0.f;
#pragma unroll
            for (int c = 0; c < C_; c++) {
                float2 f = __half22float2(
                    part2[((size_t)(b * C_ + c) * SL2_ + s) * N_ + n]);
                a0 += f.x; a1 += f.y;
            }
            sA[p * SAS2 + s * 2 + 0] = (_Float16)a0;
            sA[p * SAS2 + s * 2 + 1] = (_Float16)a1;
        }
    }

    floatx4 acc[8];
#pragma unroll
    for (int nt = 0; nt < 8; nt++) acc[nt] = (floatx4)(0.f);

    // ---- GEMM1: tmp = agg @ vp_w^T ----
    for (int kc = 0; kc < 256 / KC; kc++) {
        __syncthreads();
        {   // stage vp_w chunk: 2 threads per e-row, 32 k f32 -> f16 each
            const int row = tid >> 1, half = tid & 1;
            const float* src = vp_w + (size_t)row * 256 + kc * KC + half * 32;
            _Float16* dst = &wS[row * WSS2 + half * 32];
#pragma unroll
            for (int i = 0; i < 4; i++) {
                float4 v = *(const float4*)(src + i * 8);
                float4 u = *(const float4*)(src + i * 8 + 4);
                half8 h = {(_Float16)v.x, (_Float16)v.y, (_Float16)v.z, (_Float16)v.w,
                           (_Float16)u.x, (_Float16)u.y, (_Float16)u.z, (_Float16)u.w};
                *(half8*)(dst + i * 8) = h;
            }
        }
        __syncthreads();
#pragma unroll
        for (int ks = 0; ks < KC / 32; ks++) {
            half8 a = *(half8*)&sA[(mt * 16 + col) * SAS2 + kc * KC + ks * 32 + q * 8];
#pragma unroll
            for (int nt = 0; nt < 8; nt++) {
                half8 bf = *(half8*)&wS[(nh * 128 + nt * 16 + col) * WSS2 + ks * 32 + q * 8];
                acc[nt] = __builtin_amdgcn_mfma_f32_16x16x32_f16(a, bf, acc[nt], 0, 0, 0);
            }
        }
    }

    // ---- middle: tmp = acc + vp_b + inst -> sT (f16); reset acc ----
#pragma unroll
    for (int nt = 0; nt < 8; nt++) {
        const int e = nh * 128 + nt * 16 + col;
        const float bv = vp_b[e];
#pragma unroll
        for (int r = 0; r < 4; r++) {
            const int p = mt * 16 + q * 4 + r;
            float t = acc[nt][r] + bv + inst[(size_t)(p0 + p) * E_ + e];
            sT[p * SAS2 + e] = (_Float16)t;
        }
        acc[nt] = (floatx4)(0.f);
    }

    // ---- GEMM2: out = tmp @ op_w^T ----
    for (int kc = 0; kc < 256 / KC; kc++) {
        __syncthreads();
        {
            const int row = tid >> 1, half = tid & 1;
            const float* src = op_w + (size_t)row * 256 + kc * KC + half * 32;
            _Float16* dst = &wS[row * WSS2 + half * 32];
#pragma unroll
            for (int i = 0; i < 4; i++) {
                float4 v = *(const float4*)(src + i * 8);
                float4 u = *(const float4*)(src + i * 8 + 4);
                half8 h = {(_Float16)v.x, (_Float16)v.y, (_Float16)v.z, (_Float16)v.w,
                           (_Float16)u.x, (_Float16)u.y, (_Float16)u.z, (_Float16)u.w};
                *(half8*)(dst + i * 8) = h;
            }
        }
        __syncthreads();
#pragma unroll
        for (int ks = 0; ks < KC / 32; ks++) {
            half8 a = *(half8*)&sT[(mt * 16 + col) * SAS2 + kc * KC + ks * 32 + q * 8];
#pragma unroll
            for (int nt = 0; nt < 8; nt++) {
                half8 bf = *(half8*)&wS[(nh * 128 + nt * 16 + col) * WSS2 + ks * 32 + q * 8];
                acc[nt] = __builtin_amdgcn_mfma_f32_16x16x32_f16(a, bf, acc[nt], 0, 0, 0);
            }
        }
    }

    // ---- store out + op_b ----
#pragma unroll
    for (int nt = 0; nt < 8; nt++) {
        const int e = nh * 128 + nt * 16 + col;
        const float ob = op_b[e];
#pragma unroll
        for (int r = 0; r < 4; r++) {
            const int p = mt * 16 + q * 4 + r;
            out[(size_t)(p0 + p) * E_ + e] = acc[nt][r] + ob;
        }
    }
}

// ---------------------------------------------------------------------------
// Fallback VALU epilogue (atomic path, PART=false). (unchanged)
// ---------------------------------------------------------------------------
#define PT 32
#define SAS 264
#define WSS 36

__global__ __launch_bounds__(256) void gemm_valu(
    const float* __restrict__ inst,
    const float* __restrict__ vp_w, const float* __restrict__ vp_b,
    const float* __restrict__ op_w, const float* __restrict__ op_b,
    float* __restrict__ io)
{
    __shared__ __align__(16) float sA[PT * SAS];
    __shared__ __align__(16) float wS[256 * WSS];

    const int tid = threadIdx.x;
    const int eg = tid & 31;
    const int pg = tid >> 5;
    const int p0 = blockIdx.x * PT;

#pragma unroll
    for (int r = 0; r < PT; r++)
        sA[r * SAS + tid] = io[(size_t)(p0 + r) * E_ + tid];
    __syncthreads();

    float acc[4][8];
#pragma unroll
    for (int j = 0; j < 4; j++)
#pragma unroll
        for (int i = 0; i < 8; i++) acc[j][i] = 0.f;

    for (int k0 = 0; k0 < 256; k0 += 32) {
        __syncthreads();
#pragma unroll
        for (int r = 0; r < 32; r++) {
            int lin = r * 256 + tid;
            int e = lin >> 5, kk = lin & 31;
            wS[e * WSS + kk] = vp_w[(size_t)e * 256 + k0 + kk];
        }
        __syncthreads();
#pragma unroll
        for (int kk = 0; kk < 32; kk += 4) {
            float4 wv4[8], av4[4];
#pragma unroll
            for (int i = 0; i < 8; i++)
                wv4[i] = *(const float4*)&wS[(eg + 32 * i) * WSS + kk];
#pragma unroll
            for (int j = 0; j < 4; j++)
                av4[j] = *(const float4*)&sA[(pg * 4 + j) * SAS + k0 + kk];
#pragma unroll
            for (int j = 0; j < 4; j++)
#pragma unroll
                for (int i = 0; i < 8; i++)
                    acc[j][i] += av4[j].x * wv4[i].x + av4[j].y * wv4[i].y
                               + av4[j].z * wv4[i].z + av4[j].w * wv4[i].w;
        }
    }

    __syncthreads();
#pragma unroll
    for (int j = 0; j < 4; j++) {
        int p = pg * 4 + j;
#pragma unroll
        for (int i = 0; i < 8; i++) {
            int e = eg + 32 * i;
            float t = acc[j][i] + vp_b[e] + inst[(size_t)(p0 + p) * E_ + e];
            sA[p * SAS + e] = t;
            acc[j][i] = 0.f;
        }
    }

    for (int k0 = 0; k0 < 256; k0 += 32) {
        __syncthreads();
#pragma unroll
        for (int r = 0; r < 32; r++) {
            int lin = r * 256 + tid;
            int e = lin >> 5, kk = lin & 31;
            wS[e * WSS + kk] = op_w[(size_t)e * 256 + k0 + kk];
        }
        __syncthreads();
#pragma unroll
        for (int kk = 0; kk < 32; kk += 4) {
            float4 wv4[8], av4[4];
#pragma unroll
            for (int i = 0; i < 8; i++)
                wv4[i] = *(const float4*)&wS[(eg + 32 * i) * WSS + kk];
#pragma unroll
            for (int j = 0; j < 4; j++)
                av4[j] = *(const float4*)&sA[(pg * 4 + j) * SAS + k0 + kk];
#pragma unroll
            for (int j = 0; j < 4; j++)
#pragma unroll
                for (int i = 0; i < 8; i++)
                    acc[j][i] += av4[j].x * wv4[i].x + av4[j].y * wv4[i].y
                               + av4[j].z * wv4[i].z + av4[j].w * wv4[i].w;
        }
    }

#pragma unroll
    for (int j = 0; j < 4; j++) {
        int p = pg * 4 + j;
#pragma unroll
        for (int i = 0; i < 8; i++) {
            int e = eg + 32 * i;
            io[(size_t)(p0 + p) * E_ + e] = acc[j][i] + op_b[e];
        }
    }
}

// ---------------------------------------------------------------------------
extern "C" void kernel_launch(void* const* d_in, const int* in_sizes, int n_in,
                              void* d_out, int out_size, void* d_ws, size_t ws_size,
                              hipStream_t stream)
{
    const float* inst   = (const float*)d_in[0];
    const float* anchor = (const float*)d_in[1];
    const float* proj   = (const float*)d_in[2];
    const float* f0     = (const float*)d_in[3];
    const float* f1     = (const float*)d_in[4];
    const float* f2     = (const float*)d_in[5];
    const float* f3     = (const float*)d_in[6];
    const float* attn_w = (const float*)d_in[7];
    const float* attn_b = (const float*)d_in[8];
    const float* vp_w   = (const float*)d_in[9];
    const float* vp_b   = (const float*)d_in[10];
    const float* op_w   = (const float*)d_in[11];
    const float* op_b   = (const float*)d_in[12];
    float* out = (float*)d_out;

    // ws layout: meta_w (32 B/pt) | meta_b (16 B/pt) | partials (fp16, 39 MB)
    const size_t NPT = (size_t)B_ * C_ * N_;
    uint4* meta_w = (uint4*)d_ws;
    int4* meta_b = (int4*)((char*)d_ws + NPT * 32);
    __half2* part2 = (__half2*)((char*)d_ws + NPT * 48);
    const size_t part2_bytes = (size_t)B_ * C_ * SL2_ * N_ * sizeof(__half2);
    const size_t need = NPT * 48 + part2_bytes;

    prep_kernel<<<(B_ * N_) / 256, 256, 0, stream>>>(
        inst, anchor, proj, attn_w, attn_b, meta_w, meta_b);

    if (ws_size >= need) {
        gather_t<true><<<B_ * C_ * SL2_, 1024, 0, stream>>>(
            f0, f1, f2, f3, meta_w, meta_b, part2, out);
        gemm_mfma<<<(B_ * N_) / 64, 512, 0, stream>>>(
            inst, vp_w, vp_b, op_w, op_b, part2, out);
    } else {
        hipMemsetAsync(d_out, 0, (size_t)out_size * sizeof(float), stream);
        gather_t<false><<<B_ * C_ * SL2_, 1024, 0, stream>>>(
            f0, f1, f2, f3, meta_w, meta_b, part2, out);
        gemm_valu<<<(B_ * N_) / PT, 256, 0, stream>>>(
            inst, vp_w, vp_b, op_w, op_b, out);
    }
}

// Round 6
// 345.597 us; speedup vs baseline: 1.0496x; 1.0091x over previous
//
#include <hip/hip_runtime.h>
#include <hip/hip_fp16.h>
#include <math.h>

#define B_ 2
#define N_ 6400
#define E_ 256
#define C_ 6
#define L_ 4
#define SL2_ 128  // 2-channel slices (E/2)

// Level geometry (H, W), flattened per-channel offsets, total pixels/channel
__device__ __host__ constexpr int HWH[4] = {64, 32, 16, 8};
__device__ __host__ constexpr int HWW[4] = {176, 88, 44, 22};
__device__ __host__ constexpr int LOFF[4] = {0, 11264, 14080, 14784};
#define HWT 14960

typedef __attribute__((ext_vector_type(8))) _Float16 half8;
typedef __attribute__((ext_vector_type(4))) float floatx4;

// ---------------------------------------------------------------------------
// Kernel 1: per-point prep. (unchanged)
// ---------------------------------------------------------------------------
__global__ __launch_bounds__(256) void prep_kernel(
    const float* __restrict__ inst, const float* __restrict__ anchor,
    const float* __restrict__ proj, const float* __restrict__ attn_w,
    const float* __restrict__ attn_b,
    uint4* __restrict__ meta_w, int4* __restrict__ meta_b)
{
    __shared__ float AWT[256 * 24];   // attn_w transposed [k][j]
    __shared__ float ts[256 * 33];    // inst tile [point][k-chunk], padded

    const int tid = threadIdx.x;

    for (int idx = tid; idx < 24 * 256; idx += 256) {
        int j = idx >> 8, k = idx & 255;
        AWT[k * 24 + j] = attn_w[idx];
    }
    __syncthreads();

    const int pt0 = blockIdx.x * 256;

    float acc[24];
#pragma unroll
    for (int j = 0; j < 24; j++) acc[j] = attn_b[j];

    for (int k0 = 0; k0 < 256; k0 += 32) {
#pragma unroll
        for (int r = 0; r < 32; r++) {
            int lin = r * 256 + tid;
            int p = lin >> 5, kk = lin & 31;
            ts[p * 33 + kk] = inst[(size_t)(pt0 + p) * 256 + k0 + kk];
        }
        __syncthreads();
#pragma unroll
        for (int kk = 0; kk < 32; kk++) {
            float v = ts[tid * 33 + kk];
            const float* aw = &AWT[(k0 + kk) * 24];
#pragma unroll
            for (int j = 0; j < 24; j++) acc[j] += v * aw[j];
        }
        __syncthreads();
    }

    const int pt = pt0 + tid;
    const int b = pt / N_;   // uniform per block (6400 % 256 == 0)
    const int n = pt - b * N_;

    float attn[24];
#pragma unroll
    for (int c = 0; c < C_; c++) {
        float m = fmaxf(fmaxf(acc[c * 4], acc[c * 4 + 1]),
                        fmaxf(acc[c * 4 + 2], acc[c * 4 + 3]));
        float s = 0.f;
#pragma unroll
        for (int l = 0; l < L_; l++) {
            float e = expf(acc[c * 4 + l] - m);
            attn[c * 4 + l] = e;
            s += e;
        }
        float r = 1.f / s;
#pragma unroll
        for (int l = 0; l < L_; l++) attn[c * 4 + l] *= r;
    }

    float ax = anchor[(size_t)pt * 11 + 0];
    float ay = anchor[(size_t)pt * 11 + 1];
    float az = anchor[(size_t)pt * 11 + 2];
    float wxp = (1.f / (1.f + expf(-ax))) * 102.4f - 51.2f;
    float wyp = (1.f / (1.f + expf(-ay))) * 102.4f - 51.2f;
    float wzp = (1.f / (1.f + expf(-az))) * 8.f - 5.f;

#pragma unroll
    for (int c = 0; c < C_; c++) {
        const float* P = &proj[(size_t)(b * C_ + c) * 16];
        float cx = P[0] * wxp + P[1] * wyp + P[2] * wzp + P[3];
        float cy = P[4] * wxp + P[5] * wyp + P[6] * wzp + P[7];
        float cz = P[8] * wxp + P[9] * wyp + P[10] * wzp + P[11];
        float d = fmaxf(cz, 1e-4f);
        float u = cx / d, v = cy / d;

        float x0f = floorf(u), y0f = floorf(v);
        float fx1 = u - x0f, fy1 = v - y0f;
        float fx0 = 1.f - fx1, fy0 = 1.f - fy1;

        float4 wl[4]; int bsx[4];
#pragma unroll
        for (int l = 0; l < L_; l++) {
            const int W = HWW[l], H = HWH[l];
            float ax0, ax1; int bx;
            int ix = (int)fminf(fmaxf(x0f, -2.f), (float)W);
            if (ix <= -2 || ix >= W)      { ax0 = 0.f;  ax1 = 0.f;  bx = 0; }
            else if (ix == -1)            { ax0 = fx1;  ax1 = 0.f;  bx = 0; }
            else if (ix == W - 1)         { ax0 = 0.f;  ax1 = fx0;  bx = W - 2; }
            else                          { ax0 = fx0;  ax1 = fx1;  bx = ix; }
            float ay0, ay1; int by;
            int iy = (int)fminf(fmaxf(y0f, -2.f), (float)H);
            if (iy <= -2 || iy >= H)      { ay0 = 0.f;  ay1 = 0.f;  by = 0; }
            else if (iy == -1)            { ay0 = fy1;  ay1 = 0.f;  by = 0; }
            else if (iy == H - 1)         { ay0 = 0.f;  ay1 = fy0;  by = H - 2; }
            else                          { ay0 = fy0;  ay1 = fy1;  by = iy; }

            float a = attn[c * 4 + l];
            wl[l] = make_float4(a * ay0 * ax0, a * ay0 * ax1,
                                a * ay1 * ax0, a * ay1 * ax1);
            bsx[l] = by * W + bx;
        }
        size_t mi = (size_t)(b * C_ + c) * N_ + n;
        union { uint4 u; __half2 h[4]; } q0, q1;
        q0.h[0] = __floats2half2_rn(wl[0].x, wl[0].y);
        q0.h[1] = __floats2half2_rn(wl[0].z, wl[0].w);
        q0.h[2] = __floats2half2_rn(wl[1].x, wl[1].y);
        q0.h[3] = __floats2half2_rn(wl[1].z, wl[1].w);
        q1.h[0] = __floats2half2_rn(wl[2].x, wl[2].y);
        q1.h[1] = __floats2half2_rn(wl[2].z, wl[2].w);
        q1.h[2] = __floats2half2_rn(wl[3].x, wl[3].y);
        q1.h[3] = __floats2half2_rn(wl[3].z, wl[3].w);
        meta_w[mi * 2 + 0] = q0.u;
        meta_w[mi * 2 + 1] = q1.u;
        meta_b[mi] = make_int4(bsx[0], bsx[1], bsx[2], bsx[3]);
    }
}

// ---------------------------------------------------------------------------
// Kernel 2: gather, dense store, branch-free levels (weights are >= 0 and
// exactly 0 for invisible corners, so unconditional FMA == reference).
// XCD-chunked blockIdx swizzle + depth-2 meta prefetch.
// part2 layout: __half2[((b*C+c)*SL2 + slice)*N + n].
// ---------------------------------------------------------------------------
template<bool PART>
__global__ __launch_bounds__(1024) void gather_t(
    const float* __restrict__ f0, const float* __restrict__ f1,
    const float* __restrict__ f2, const float* __restrict__ f3,
    const uint4* __restrict__ meta_w, const int4* __restrict__ meta_b,
    __half2* __restrict__ part2, float* __restrict__ agg)
{
    __shared__ __half2 lds2[HWT];   // 59840 B

    const int tid = threadIdx.x;
    int bid = blockIdx.x;
    bid = (bid & 7) * 192 + (bid >> 3);   // XCD chunking (grid = 1536 = 8*192)
    const int slice = bid & 127;          // E/2 = 128 slices
    const int c = (bid >> 7) % C_;
    const int b = bid / (128 * C_);
    const int e0 = slice * 2;
    const int bc = b * C_ + c;

    const float* fs[4] = {f0, f1, f2, f3};

#pragma unroll
    for (int l = 0; l < L_; l++) {
        const int HW = HWH[l] * HWW[l];
        const float* s0 = fs[l] + (size_t)(bc * E_ + e0) * HW;
        const float* s1 = s0 + HW;
        const int quarter = HW >> 2;
        for (int q = tid; q < quarter; q += 1024) {
            int p = q * 4;
            float4 v0 = *(const float4*)(s0 + p);
            float4 v1 = *(const float4*)(s1 + p);
            union { uint4 u; __half2 h[4]; } pk;
            pk.h[0] = __floats2half2_rn(v0.x, v1.x);
            pk.h[1] = __floats2half2_rn(v0.y, v1.y);
            pk.h[2] = __floats2half2_rn(v0.z, v1.z);
            pk.h[3] = __floats2half2_rn(v0.w, v1.w);
            *(uint4*)&lds2[LOFF[l] + p] = pk.u;
        }
    }
    __syncthreads();

    const size_t mbase = (size_t)bc * N_;
    const uint4* mwp = meta_w + mbase * 2;
    const int4* mbp = meta_b + mbase;
    __half2* pout = part2 + ((size_t)bc * SL2_ + slice) * N_;
    float* aggb = agg + (size_t)b * N_ * E_ + e0;

    int n = tid;
    uint4 m0, m1; int4 px;       // current
    uint4 o0, o1; int4 ox;       // next (n+1024)
    {
        m0 = mwp[(size_t)n * 2];
        m1 = mwp[(size_t)n * 2 + 1];
        px = mbp[n];
    }
    if (n + 1024 < N_) {
        o0 = mwp[(size_t)(n + 1024) * 2];
        o1 = mwp[(size_t)(n + 1024) * 2 + 1];
        ox = mbp[n + 1024];
    }

    while (n < N_) {
        const int n2 = n + 2048;
        uint4 t0, t1; int4 tx;
        if (n2 < N_) {
            t0 = mwp[(size_t)n2 * 2];
            t1 = mwp[(size_t)n2 * 2 + 1];
            tx = mbp[n2];
        }

        union { uint4 u; __half2 h[4]; } a0u, a1u;
        a0u.u = m0; a1u.u = m1;
        __half2 wh[8];
        wh[0] = a0u.h[0]; wh[1] = a0u.h[1]; wh[2] = a0u.h[2]; wh[3] = a0u.h[3];
        wh[4] = a1u.h[0]; wh[5] = a1u.h[1]; wh[6] = a1u.h[2]; wh[7] = a1u.h[3];

        const int pxs[4] = {px.x, px.y, px.z, px.w};

        float p0[4], p1[4];
#pragma unroll
        for (int l = 0; l < L_; l++) {
            const int W = HWW[l];
            const int base = LOFF[l] + pxs[l];
            float2 wab = __half22float2(wh[l * 2]);      // w00, w01
            float2 wcd = __half22float2(wh[l * 2 + 1]);  // w10, w11
            float2 f00 = __half22float2(lds2[base]);
            float2 f01 = __half22float2(lds2[base + 1]);
            float2 f10 = __half22float2(lds2[base + W]);
            float2 f11 = __half22float2(lds2[base + W + 1]);
            p0[l] = (wab.x * f00.x + wab.y * f01.x)
                  + (wcd.x * f10.x + wcd.y * f11.x);
            p1[l] = (wab.x * f00.y + wab.y * f01.y)
                  + (wcd.x * f10.y + wcd.y * f11.y);
        }
        float a0 = (p0[0] + p0[1]) + (p0[2] + p0[3]);
        float a1 = (p1[0] + p1[1]) + (p1[2] + p1[3]);

        if (PART) {
            pout[n] = __floats2half2_rn(a0, a1);   // coalesced 4 B store
        } else {
            if (a0 != 0.f || a1 != 0.f) {
                float* dst = aggb + (size_t)n * E_;
                atomicAdd(dst + 0, a0);
                atomicAdd(dst + 1, a1);
            }
        }

        n += 1024;
        m0 = o0; m1 = o1; px = ox;
        o0 = t0; o1 = t1; ox = tx;
    }
}

// ---------------------------------------------------------------------------
// Kernel 3 (main path): MFMA f16 epilogue, 128-point tiles / 1024 threads.
// tmp overwrites sA in place (extra barrier guards the GEMM1-read ->
// tmp-write hazard). Weight staging: once per 128 points (4x less than the
// original 32-pt version). LDS: sA 66 KB + wS 36 KB = 102 KB, 1 block/CU.
// 16 waves: 8 m-tiles (16 pts) x 2 col-halves (128 e).
// ---------------------------------------------------------------------------
#define SAS2 264   // sA row stride (halves)
#define WSS2 72    // wS row stride (halves)
#define KC 64      // k-chunk

__global__ __launch_bounds__(1024, 4) void gemm_mfma(
    const float* __restrict__ inst,
    const float* __restrict__ vp_w, const float* __restrict__ vp_b,
    const float* __restrict__ op_w, const float* __restrict__ op_b,
    const __half2* __restrict__ part2, float* __restrict__ out)
{
    __shared__ _Float16 sA[128 * SAS2];  // 67584 B
    __shared__ _Float16 wS[256 * WSS2];  // 36864 B

    const int tid = threadIdx.x;
    const int wave = tid >> 6;
    const int lane = tid & 63;
    const int mt = wave & 7;        // m-tile (16 points), 8 tiles
    const int nh = wave >> 3;       // col half (128 e)
    const int q = lane >> 4;        // quad
    const int col = lane & 15;

    const int p0 = blockIdx.x * 128;
    const int b = p0 / N_;                   // tile never crosses b (6400%128==0)
    const int nbase = p0 - b * N_;

    // ---- stage sA: reduce 6 cam partials (2-ch slices), f32 acc -> f16 ----
    {
        const int p = tid & 127, sg = tid >> 7;   // 8 slice-groups
        const int n = nbase + p;
        for (int s = sg; s < SL2_; s += 8) {
            float a0 = 0.f, a1 = 0.f;
#pragma unroll
            for (int c = 0; c < C_; c++) {
                float2 f = __half22float2(
                    part2[((size_t)(b * C_ + c) * SL2_ + s) * N_ + n]);
                a0 += f.x; a1 += f.y;
            }
            sA[p * SAS2 + s * 2 + 0] = (_Float16)a0;
            sA[p * SAS2 + s * 2 + 1] = (_Float16)a1;
        }
    }

    floatx4 acc[8];
#pragma unroll
    for (int nt = 0; nt < 8; nt++) acc[nt] = (floatx4)(0.f);

    // ---- GEMM1: tmp = agg @ vp_w^T ----
    for (int kc = 0; kc < 256 / KC; kc++) {
        __syncthreads();
        {   // stage vp_w chunk: 4 threads per e-row, 16 k f32 -> f16 each
            const int row = tid >> 2, qt = tid & 3;
            const float* src = vp_w + (size_t)row * 256 + kc * KC + qt * 16;
            _Float16* dst = &wS[row * WSS2 + qt * 16];
#pragma unroll
            for (int i = 0; i < 2; i++) {
                float4 v = *(const float4*)(src + i * 8);
                float4 u = *(const float4*)(src + i * 8 + 4);
                half8 h = {(_Float16)v.x, (_Float16)v.y, (_Float16)v.z, (_Float16)v.w,
                           (_Float16)u.x, (_Float16)u.y, (_Float16)u.z, (_Float16)u.w};
                *(half8*)(dst + i * 8) = h;
            }
        }
        __syncthreads();
#pragma unroll
        for (int ks = 0; ks < KC / 32; ks++) {
            half8 a = *(half8*)&sA[(mt * 16 + col) * SAS2 + kc * KC + ks * 32 + q * 8];
#pragma unroll
            for (int nt = 0; nt < 8; nt++) {
                half8 bf = *(half8*)&wS[(nh * 128 + nt * 16 + col) * WSS2 + ks * 32 + q * 8];
                acc[nt] = __builtin_amdgcn_mfma_f32_16x16x32_f16(a, bf, acc[nt], 0, 0, 0);
            }
        }
    }

    // ---- middle: tmp = acc + vp_b + inst -> sA IN PLACE; reset acc ----
    __syncthreads();   // all GEMM1 reads of sA must complete before overwrite
#pragma unroll
    for (int nt = 0; nt < 8; nt++) {
        const int e = nh * 128 + nt * 16 + col;
        const float bv = vp_b[e];
#pragma unroll
        for (int r = 0; r < 4; r++) {
            const int p = mt * 16 + q * 4 + r;
            float t = acc[nt][r] + bv + inst[(size_t)(p0 + p) * E_ + e];
            sA[p * SAS2 + e] = (_Float16)t;
        }
        acc[nt] = (floatx4)(0.f);
    }

    // ---- GEMM2: out = tmp @ op_w^T ----
    for (int kc = 0; kc < 256 / KC; kc++) {
        __syncthreads();
        {
            const int row = tid >> 2, qt = tid & 3;
            const float* src = op_w + (size_t)row * 256 + kc * KC + qt * 16;
            _Float16* dst = &wS[row * WSS2 + qt * 16];
#pragma unroll
            for (int i = 0; i < 2; i++) {
                float4 v = *(const float4*)(src + i * 8);
                float4 u = *(const float4*)(src + i * 8 + 4);
                half8 h = {(_Float16)v.x, (_Float16)v.y, (_Float16)v.z, (_Float16)v.w,
                           (_Float16)u.x, (_Float16)u.y, (_Float16)u.z, (_Float16)u.w};
                *(half8*)(dst + i * 8) = h;
            }
        }
        __syncthreads();
#pragma unroll
        for (int ks = 0; ks < KC / 32; ks++) {
            half8 a = *(half8*)&sA[(mt * 16 + col) * SAS2 + kc * KC + ks * 32 + q * 8];
#pragma unroll
            for (int nt = 0; nt < 8; nt++) {
                half8 bf = *(half8*)&wS[(nh * 128 + nt * 16 + col) * WSS2 + ks * 32 + q * 8];
                acc[nt] = __builtin_amdgcn_mfma_f32_16x16x32_f16(a, bf, acc[nt], 0, 0, 0);
            }
        }
    }

    // ---- store out + op_b ----
#pragma unroll
    for (int nt = 0; nt < 8; nt++) {
        const int e = nh * 128 + nt * 16 + col;
        const float ob = op_b[e];
#pragma unroll
        for (int r = 0; r < 4; r++) {
            const int p = mt * 16 + q * 4 + r;
            out[(size_t)(p0 + p) * E_ + e] = acc[nt][r] + ob;
        }
    }
}

// ---------------------------------------------------------------------------
// Fallback VALU epilogue (atomic path, PART=false). (unchanged)
// ---------------------------------------------------------------------------
#define PT 32
#define SAS 264
#define WSS 36

__global__ __launch_bounds__(256) void gemm_valu(
    const float* __restrict__ inst,
    const float* __restrict__ vp_w, const float* __restrict__ vp_b,
    const float* __restrict__ op_w, const float* __restrict__ op_b,
    float* __restrict__ io)
{
    __shared__ __align__(16) float sA[PT * SAS];
    __shared__ __align__(16) float wS[256 * WSS];

    const int tid = threadIdx.x;
    const int eg = tid & 31;
    const int pg = tid >> 5;
    const int p0 = blockIdx.x * PT;

#pragma unroll
    for (int r = 0; r < PT; r++)
        sA[r * SAS + tid] = io[(size_t)(p0 + r) * E_ + tid];
    __syncthreads();

    float acc[4][8];
#pragma unroll
    for (int j = 0; j < 4; j++)
#pragma unroll
        for (int i = 0; i < 8; i++) acc[j][i] = 0.f;

    for (int k0 = 0; k0 < 256; k0 += 32) {
        __syncthreads();
#pragma unroll
        for (int r = 0; r < 32; r++) {
            int lin = r * 256 + tid;
            int e = lin >> 5, kk = lin & 31;
            wS[e * WSS + kk] = vp_w[(size_t)e * 256 + k0 + kk];
        }
        __syncthreads();
#pragma unroll
        for (int kk = 0; kk < 32; kk += 4) {
            float4 wv4[8], av4[4];
#pragma unroll
            for (int i = 0; i < 8; i++)
                wv4[i] = *(const float4*)&wS[(eg + 32 * i) * WSS + kk];
#pragma unroll
            for (int j = 0; j < 4; j++)
                av4[j] = *(const float4*)&sA[(pg * 4 + j) * SAS + k0 + kk];
#pragma unroll
            for (int j = 0; j < 4; j++)
#pragma unroll
                for (int i = 0; i < 8; i++)
                    acc[j][i] += av4[j].x * wv4[i].x + av4[j].y * wv4[i].y
                               + av4[j].z * wv4[i].z + av4[j].w * wv4[i].w;
        }
    }

    __syncthreads();
#pragma unroll
    for (int j = 0; j < 4; j++) {
        int p = pg * 4 + j;
#pragma unroll
        for (int i = 0; i < 8; i++) {
            int e = eg + 32 * i;
            float t = acc[j][i] + vp_b[e] + inst[(size_t)(p0 + p) * E_ + e];
            sA[p * SAS + e] = t;
            acc[j][i] = 0.f;
        }
    }

    for (int k0 = 0; k0 < 256; k0 += 32) {
        __syncthreads();
#pragma unroll
        for (int r = 0; r < 32; r++) {
            int lin = r * 256 + tid;
            int e = lin >> 5, kk = lin & 31;
            wS[e * WSS + kk] = op_w[(size_t)e * 256 + k0 + kk];
        }
        __syncthreads();
#pragma unroll
        for (int kk = 0; kk < 32; kk += 4) {
            float4 wv4[8], av4[4];
#pragma unroll
            for (int i = 0; i < 8; i++)
                wv4[i] = *(const float4*)&wS[(eg + 32 * i) * WSS + kk];
#pragma unroll
            for (int j = 0; j < 4; j++)
                av4[j] = *(const float4*)&sA[(pg * 4 + j) * SAS + k0 + kk];
#pragma unroll
            for (int j = 0; j < 4; j++)
#pragma unroll
                for (int i = 0; i < 8; i++)
                    acc[j][i] += av4[j].x * wv4[i].x + av4[j].y * wv4[i].y
                               + av4[j].z * wv4[i].z + av4[j].w * wv4[i].w;
        }
    }

#pragma unroll
    for (int j = 0; j < 4; j++) {
        int p = pg * 4 + j;
#pragma unroll
        for (int i = 0; i < 8; i++) {
            int e = eg + 32 * i;
            io[(size_t)(p0 + p) * E_ + e] = acc[j][i] + op_b[e];
        }
    }
}

// ---------------------------------------------------------------------------
extern "C" void kernel_launch(void* const* d_in, const int* in_sizes, int n_in,
                              void* d_out, int out_size, void* d_ws, size_t ws_size,
                              hipStream_t stream)
{
    const float* inst   = (const float*)d_in[0];
    const float* anchor = (const float*)d_in[1];
    const float* proj   = (const float*)d_in[2];
    const float* f0     = (const float*)d_in[3];
    const float* f1     = (const float*)d_in[4];
    const float* f2     = (const float*)d_in[5];
    const float* f3     = (const float*)d_in[6];
    const float* attn_w = (const float*)d_in[7];
    const float* attn_b = (const float*)d_in[8];
    const float* vp_w   = (const float*)d_in[9];
    const float* vp_b   = (const float*)d_in[10];
    const float* op_w   = (const float*)d_in[11];
    const float* op_b   = (const float*)d_in[12];
    float* out = (float*)d_out;

    // ws layout: meta_w (32 B/pt) | meta_b (16 B/pt) | partials (fp16, 39 MB)
    const size_t NPT = (size_t)B_ * C_ * N_;
    uint4* meta_w = (uint4*)d_ws;
    int4* meta_b = (int4*)((char*)d_ws + NPT * 32);
    __half2* part2 = (__half2*)((char*)d_ws + NPT * 48);
    const size_t part2_bytes = (size_t)B_ * C_ * SL2_ * N_ * sizeof(__half2);
    const size_t need = NPT * 48 + part2_bytes;

    prep_kernel<<<(B_ * N_) / 256, 256, 0, stream>>>(
        inst, anchor, proj, attn_w, attn_b, meta_w, meta_b);

    if (ws_size >= need) {
        gather_t<true><<<B_ * C_ * SL2_, 1024, 0, stream>>>(
            f0, f1, f2, f3, meta_w, meta_b, part2, out);
        gemm_mfma<<<(B_ * N_) / 128, 1024, 0, stream>>>(
            inst, vp_w, vp_b, op_w, op_b, part2, out);
    } else {
        hipMemsetAsync(d_out, 0, (size_t)out_size * sizeof(float), stream);
        gather_t<false><<<B_ * C_ * SL2_, 1024, 0, stream>>>(
            f0, f1, f2, f3, meta_w, meta_b, part2, out);
        gemm_valu<<<(B_ * N_) / PT, 256, 0, stream>>>(
            inst, vp_w, vp_b, op_w, op_b, out);
    }
}

// Round 7
// 342.715 us; speedup vs baseline: 1.0584x; 1.0084x over previous
//
#include <hip/hip_runtime.h>
#include <hip/hip_fp16.h>
#include <math.h>

#define B_ 2
#define N_ 6400
#define E_ 256
#define C_ 6
#define L_ 4
#define SL2_ 128  // 2-channel slices (E/2)

// Level geometry (H, W), flattened per-channel offsets, total pixels/channel
__device__ __host__ constexpr int HWH[4] = {64, 32, 16, 8};
__device__ __host__ constexpr int HWW[4] = {176, 88, 44, 22};
__device__ __host__ constexpr int LOFF[4] = {0, 11264, 14080, 14784};
#define HWT 14960

typedef __attribute__((ext_vector_type(8))) _Float16 half8;
typedef __attribute__((ext_vector_type(4))) float floatx4;

// ---------------------------------------------------------------------------
// Kernel 1: per-point prep. (unchanged)
// ---------------------------------------------------------------------------
__global__ __launch_bounds__(256) void prep_kernel(
    const float* __restrict__ inst, const float* __restrict__ anchor,
    const float* __restrict__ proj, const float* __restrict__ attn_w,
    const float* __restrict__ attn_b,
    uint4* __restrict__ meta_w, int4* __restrict__ meta_b)
{
    __shared__ float AWT[256 * 24];   // attn_w transposed [k][j]
    __shared__ float ts[256 * 33];    // inst tile [point][k-chunk], padded

    const int tid = threadIdx.x;

    for (int idx = tid; idx < 24 * 256; idx += 256) {
        int j = idx >> 8, k = idx & 255;
        AWT[k * 24 + j] = attn_w[idx];
    }
    __syncthreads();

    const int pt0 = blockIdx.x * 256;

    float acc[24];
#pragma unroll
    for (int j = 0; j < 24; j++) acc[j] = attn_b[j];

    for (int k0 = 0; k0 < 256; k0 += 32) {
#pragma unroll
        for (int r = 0; r < 32; r++) {
            int lin = r * 256 + tid;
            int p = lin >> 5, kk = lin & 31;
            ts[p * 33 + kk] = inst[(size_t)(pt0 + p) * 256 + k0 + kk];
        }
        __syncthreads();
#pragma unroll
        for (int kk = 0; kk < 32; kk++) {
            float v = ts[tid * 33 + kk];
            const float* aw = &AWT[(k0 + kk) * 24];
#pragma unroll
            for (int j = 0; j < 24; j++) acc[j] += v * aw[j];
        }
        __syncthreads();
    }

    const int pt = pt0 + tid;
    const int b = pt / N_;   // uniform per block (6400 % 256 == 0)
    const int n = pt - b * N_;

    float attn[24];
#pragma unroll
    for (int c = 0; c < C_; c++) {
        float m = fmaxf(fmaxf(acc[c * 4], acc[c * 4 + 1]),
                        fmaxf(acc[c * 4 + 2], acc[c * 4 + 3]));
        float s = 0.f;
#pragma unroll
        for (int l = 0; l < L_; l++) {
            float e = expf(acc[c * 4 + l] - m);
            attn[c * 4 + l] = e;
            s += e;
        }
        float r = 1.f / s;
#pragma unroll
        for (int l = 0; l < L_; l++) attn[c * 4 + l] *= r;
    }

    float ax = anchor[(size_t)pt * 11 + 0];
    float ay = anchor[(size_t)pt * 11 + 1];
    float az = anchor[(size_t)pt * 11 + 2];
    float wxp = (1.f / (1.f + expf(-ax))) * 102.4f - 51.2f;
    float wyp = (1.f / (1.f + expf(-ay))) * 102.4f - 51.2f;
    float wzp = (1.f / (1.f + expf(-az))) * 8.f - 5.f;

#pragma unroll
    for (int c = 0; c < C_; c++) {
        const float* P = &proj[(size_t)(b * C_ + c) * 16];
        float cx = P[0] * wxp + P[1] * wyp + P[2] * wzp + P[3];
        float cy = P[4] * wxp + P[5] * wyp + P[6] * wzp + P[7];
        float cz = P[8] * wxp + P[9] * wyp + P[10] * wzp + P[11];
        float d = fmaxf(cz, 1e-4f);
        float u = cx / d, v = cy / d;

        float x0f = floorf(u), y0f = floorf(v);
        float fx1 = u - x0f, fy1 = v - y0f;
        float fx0 = 1.f - fx1, fy0 = 1.f - fy1;

        float4 wl[4]; int bsx[4];
#pragma unroll
        for (int l = 0; l < L_; l++) {
            const int W = HWW[l], H = HWH[l];
            float ax0, ax1; int bx;
            int ix = (int)fminf(fmaxf(x0f, -2.f), (float)W);
            if (ix <= -2 || ix >= W)      { ax0 = 0.f;  ax1 = 0.f;  bx = 0; }
            else if (ix == -1)            { ax0 = fx1;  ax1 = 0.f;  bx = 0; }
            else if (ix == W - 1)         { ax0 = 0.f;  ax1 = fx0;  bx = W - 2; }
            else                          { ax0 = fx0;  ax1 = fx1;  bx = ix; }
            float ay0, ay1; int by;
            int iy = (int)fminf(fmaxf(y0f, -2.f), (float)H);
            if (iy <= -2 || iy >= H)      { ay0 = 0.f;  ay1 = 0.f;  by = 0; }
            else if (iy == -1)            { ay0 = fy1;  ay1 = 0.f;  by = 0; }
            else if (iy == H - 1)         { ay0 = 0.f;  ay1 = fy0;  by = H - 2; }
            else                          { ay0 = fy0;  ay1 = fy1;  by = iy; }

            float a = attn[c * 4 + l];
            wl[l] = make_float4(a * ay0 * ax0, a * ay0 * ax1,
                                a * ay1 * ax0, a * ay1 * ax1);
            bsx[l] = by * W + bx;
        }
        size_t mi = (size_t)(b * C_ + c) * N_ + n;
        union { uint4 u; __half2 h[4]; } q0, q1;
        q0.h[0] = __floats2half2_rn(wl[0].x, wl[0].y);
        q0.h[1] = __floats2half2_rn(wl[0].z, wl[0].w);
        q0.h[2] = __floats2half2_rn(wl[1].x, wl[1].y);
        q0.h[3] = __floats2half2_rn(wl[1].z, wl[1].w);
        q1.h[0] = __floats2half2_rn(wl[2].x, wl[2].y);
        q1.h[1] = __floats2half2_rn(wl[2].z, wl[2].w);
        q1.h[2] = __floats2half2_rn(wl[3].x, wl[3].y);
        q1.h[3] = __floats2half2_rn(wl[3].z, wl[3].w);
        meta_w[mi * 2 + 0] = q0.u;
        meta_w[mi * 2 + 1] = q1.u;
        meta_b[mi] = make_int4(bsx[0], bsx[1], bsx[2], bsx[3]);
    }
}

// ---------------------------------------------------------------------------
// Kernel 2: gather, dense store, fp16 packed point loop.
// No XCD swizzle (R0 dispatch order had the best HBM efficiency).
// Depth-2 meta prefetch. Per point: 16 ds_read_b32 (half2) + 16 hfma2
// (packed 2-channel bilinear+attention accumulate, 2 acc chains) and a
// direct 4 B fp16 store (no final cvt). Weights are exactly +0 in fp16 for
// invisible corners, so unconditional FMA == reference.
// part2 layout: __half2[((b*C+c)*SL2 + slice)*N + n].
// ---------------------------------------------------------------------------
template<bool PART>
__global__ __launch_bounds__(1024) void gather_t(
    const float* __restrict__ f0, const float* __restrict__ f1,
    const float* __restrict__ f2, const float* __restrict__ f3,
    const uint4* __restrict__ meta_w, const int4* __restrict__ meta_b,
    __half2* __restrict__ part2, float* __restrict__ agg)
{
    __shared__ __half2 lds2[HWT];   // 59840 B

    const int tid = threadIdx.x;
    const int bid = blockIdx.x;
    const int slice = bid & 127;          // E/2 = 128 slices
    const int c = (bid >> 7) % C_;
    const int b = bid / (128 * C_);
    const int e0 = slice * 2;
    const int bc = b * C_ + c;

    const float* fs[4] = {f0, f1, f2, f3};

#pragma unroll
    for (int l = 0; l < L_; l++) {
        const int HW = HWH[l] * HWW[l];
        const float* s0 = fs[l] + (size_t)(bc * E_ + e0) * HW;
        const float* s1 = s0 + HW;
        const int quarter = HW >> 2;
        for (int q = tid; q < quarter; q += 1024) {
            int p = q * 4;
            float4 v0 = *(const float4*)(s0 + p);
            float4 v1 = *(const float4*)(s1 + p);
            union { uint4 u; __half2 h[4]; } pk;
            pk.h[0] = __floats2half2_rn(v0.x, v1.x);
            pk.h[1] = __floats2half2_rn(v0.y, v1.y);
            pk.h[2] = __floats2half2_rn(v0.z, v1.z);
            pk.h[3] = __floats2half2_rn(v0.w, v1.w);
            *(uint4*)&lds2[LOFF[l] + p] = pk.u;
        }
    }
    __syncthreads();

    const size_t mbase = (size_t)bc * N_;
    const uint4* mwp = meta_w + mbase * 2;
    const int4* mbp = meta_b + mbase;
    __half2* pout = part2 + ((size_t)bc * SL2_ + slice) * N_;
    float* aggb = agg + (size_t)b * N_ * E_ + e0;

    int n = tid;
    uint4 m0, m1; int4 px;       // current
    uint4 o0, o1; int4 ox;       // next (n+1024)
    {
        m0 = mwp[(size_t)n * 2];
        m1 = mwp[(size_t)n * 2 + 1];
        px = mbp[n];
    }
    if (n + 1024 < N_) {
        o0 = mwp[(size_t)(n + 1024) * 2];
        o1 = mwp[(size_t)(n + 1024) * 2 + 1];
        ox = mbp[n + 1024];
    }

    while (n < N_) {
        const int n2 = n + 2048;
        uint4 t0, t1; int4 tx;
        if (n2 < N_) {
            t0 = mwp[(size_t)n2 * 2];
            t1 = mwp[(size_t)n2 * 2 + 1];
            tx = mbp[n2];
        }

        union { uint4 u; __half2 h[4]; } a0u, a1u;
        a0u.u = m0; a1u.u = m1;
        const int pxs[4] = {px.x, px.y, px.z, px.w};

        __half2 accA = __float2half2_rn(0.f);   // corners 00,01
        __half2 accB = __float2half2_rn(0.f);   // corners 10,11
#pragma unroll
        for (int l = 0; l < L_; l++) {
            const int W = HWW[l];
            const int base = LOFF[l] + pxs[l];
            const __half2 wp0 = (l < 2) ? a0u.h[(l & 1) * 2]     : a1u.h[(l & 1) * 2];
            const __half2 wp1 = (l < 2) ? a0u.h[(l & 1) * 2 + 1] : a1u.h[(l & 1) * 2 + 1];
            const __half2 w00 = __half2half2(__low2half(wp0));
            const __half2 w01 = __half2half2(__high2half(wp0));
            const __half2 w10 = __half2half2(__low2half(wp1));
            const __half2 w11 = __half2half2(__high2half(wp1));
            accA = __hfma2(w00, lds2[base],         accA);
            accA = __hfma2(w01, lds2[base + 1],     accA);
            accB = __hfma2(w10, lds2[base + W],     accB);
            accB = __hfma2(w11, lds2[base + W + 1], accB);
        }
        const __half2 acc = __hadd2(accA, accB);

        if (PART) {
            pout[n] = acc;                      // coalesced 4 B store, no cvt
        } else {
            float2 af = __half22float2(acc);
            if (af.x != 0.f || af.y != 0.f) {
                float* dst = aggb + (size_t)n * E_;
                atomicAdd(dst + 0, af.x);
                atomicAdd(dst + 1, af.y);
            }
        }

        n += 1024;
        m0 = o0; m1 = o1; px = ox;
        o0 = t0; o1 = t1; ox = tx;
    }
}

// ---------------------------------------------------------------------------
// Kernel 3 (main path): MFMA f16 epilogue, 128-point tiles / 1024 threads.
// (unchanged from R6)
// ---------------------------------------------------------------------------
#define SAS2 264   // sA row stride (halves)
#define WSS2 72    // wS row stride (halves)
#define KC 64      // k-chunk

__global__ __launch_bounds__(1024, 4) void gemm_mfma(
    const float* __restrict__ inst,
    const float* __restrict__ vp_w, const float* __restrict__ vp_b,
    const float* __restrict__ op_w, const float* __restrict__ op_b,
    const __half2* __restrict__ part2, float* __restrict__ out)
{
    __shared__ _Float16 sA[128 * SAS2];  // 67584 B
    __shared__ _Float16 wS[256 * WSS2];  // 36864 B

    const int tid = threadIdx.x;
    const int wave = tid >> 6;
    const int lane = tid & 63;
    const int mt = wave & 7;        // m-tile (16 points), 8 tiles
    const int nh = wave >> 3;       // col half (128 e)
    const int q = lane >> 4;        // quad
    const int col = lane & 15;

    const int p0 = blockIdx.x * 128;
    const int b = p0 / N_;                   // tile never crosses b (6400%128==0)
    const int nbase = p0 - b * N_;

    // ---- stage sA: reduce 6 cam partials (2-ch slices), f32 acc -> f16 ----
    {
        const int p = tid & 127, sg = tid >> 7;   // 8 slice-groups
        const int n = nbase + p;
        for (int s = sg; s < SL2_; s += 8) {
            float a0 = 0.f, a1 = 0.f;
#pragma unroll
            for (int c = 0; c < C_; c++) {
                float2 f = __half22float2(
                    part2[((size_t)(b * C_ + c) * SL2_ + s) * N_ + n]);
                a0 += f.x; a1 += f.y;
            }
            sA[p * SAS2 + s * 2 + 0] = (_Float16)a0;
            sA[p * SAS2 + s * 2 + 1] = (_Float16)a1;
        }
    }

    floatx4 acc[8];
#pragma unroll
    for (int nt = 0; nt < 8; nt++) acc[nt] = (floatx4)(0.f);

    // ---- GEMM1: tmp = agg @ vp_w^T ----
    for (int kc = 0; kc < 256 / KC; kc++) {
        __syncthreads();
        {   // stage vp_w chunk: 4 threads per e-row, 16 k f32 -> f16 each
            const int row = tid >> 2, qt = tid & 3;
            const float* src = vp_w + (size_t)row * 256 + kc * KC + qt * 16;
            _Float16* dst = &wS[row * WSS2 + qt * 16];
#pragma unroll
            for (int i = 0; i < 2; i++) {
                float4 v = *(const float4*)(src + i * 8);
                float4 u = *(const float4*)(src + i * 8 + 4);
                half8 h = {(_Float16)v.x, (_Float16)v.y, (_Float16)v.z, (_Float16)v.w,
                           (_Float16)u.x, (_Float16)u.y, (_Float16)u.z, (_Float16)u.w};
                *(half8*)(dst + i * 8) = h;
            }
        }
        __syncthreads();
#pragma unroll
        for (int ks = 0; ks < KC / 32; ks++) {
            half8 a = *(half8*)&sA[(mt * 16 + col) * SAS2 + kc * KC + ks * 32 + q * 8];
#pragma unroll
            for (int nt = 0; nt < 8; nt++) {
                half8 bf = *(half8*)&wS[(nh * 128 + nt * 16 + col) * WSS2 + ks * 32 + q * 8];
                acc[nt] = __builtin_amdgcn_mfma_f32_16x16x32_f16(a, bf, acc[nt], 0, 0, 0);
            }
        }
    }

    // ---- middle: tmp = acc + vp_b + inst -> sA IN PLACE; reset acc ----
    __syncthreads();   // all GEMM1 reads of sA must complete before overwrite
#pragma unroll
    for (int nt = 0; nt < 8; nt++) {
        const int e = nh * 128 + nt * 16 + col;
        const float bv = vp_b[e];
#pragma unroll
        for (int r = 0; r < 4; r++) {
            const int p = mt * 16 + q * 4 + r;
            float t = acc[nt][r] + bv + inst[(size_t)(p0 + p) * E_ + e];
            sA[p * SAS2 + e] = (_Float16)t;
        }
        acc[nt] = (floatx4)(0.f);
    }

    // ---- GEMM2: out = tmp @ op_w^T ----
    for (int kc = 0; kc < 256 / KC; kc++) {
        __syncthreads();
        {
            const int row = tid >> 2, qt = tid & 3;
            const float* src = op_w + (size_t)row * 256 + kc * KC + qt * 16;
            _Float16* dst = &wS[row * WSS2 + qt * 16];
#pragma unroll
            for (int i = 0; i < 2; i++) {
                float4 v = *(const float4*)(src + i * 8);
                float4 u = *(const float4*)(src + i * 8 + 4);
                half8 h = {(_Float16)v.x, (_Float16)v.y, (_Float16)v.z, (_Float16)v.w,
                           (_Float16)u.x, (_Float16)u.y, (_Float16)u.z, (_Float16)u.w};
                *(half8*)(dst + i * 8) = h;
            }
        }
        __syncthreads();
#pragma unroll
        for (int ks = 0; ks < KC / 32; ks++) {
            half8 a = *(half8*)&sA[(mt * 16 + col) * SAS2 + kc * KC + ks * 32 + q * 8];
#pragma unroll
            for (int nt = 0; nt < 8; nt++) {
                half8 bf = *(half8*)&wS[(nh * 128 + nt * 16 + col) * WSS2 + ks * 32 + q * 8];
                acc[nt] = __builtin_amdgcn_mfma_f32_16x16x32_f16(a, bf, acc[nt], 0, 0, 0);
            }
        }
    }

    // ---- store out + op_b ----
#pragma unroll
    for (int nt = 0; nt < 8; nt++) {
        const int e = nh * 128 + nt * 16 + col;
        const float ob = op_b[e];
#pragma unroll
        for (int r = 0; r < 4; r++) {
            const int p = mt * 16 + q * 4 + r;
            out[(size_t)(p0 + p) * E_ + e] = acc[nt][r] + ob;
        }
    }
}

// ---------------------------------------------------------------------------
// Fallback VALU epilogue (atomic path, PART=false). (unchanged)
// ---------------------------------------------------------------------------
#define PT 32
#define SAS 264
#define WSS 36

__global__ __launch_bounds__(256) void gemm_valu(
    const float* __restrict__ inst,
    const float* __restrict__ vp_w, const float* __restrict__ vp_b,
    const float* __restrict__ op_w, const float* __restrict__ op_b,
    float* __restrict__ io)
{
    __shared__ __align__(16) float sA[PT * SAS];
    __shared__ __align__(16) float wS[256 * WSS];

    const int tid = threadIdx.x;
    const int eg = tid & 31;
    const int pg = tid >> 5;
    const int p0 = blockIdx.x * PT;

#pragma unroll
    for (int r = 0; r < PT; r++)
        sA[r * SAS + tid] = io[(size_t)(p0 + r) * E_ + tid];
    __syncthreads();

    float acc[4][8];
#pragma unroll
    for (int j = 0; j < 4; j++)
#pragma unroll
        for (int i = 0; i < 8; i++) acc[j][i] = 0.f;

    for (int k0 = 0; k0 < 256; k0 += 32) {
        __syncthreads();
#pragma unroll
        for (int r = 0; r < 32; r++) {
            int lin = r * 256 + tid;
            int e = lin >> 5, kk = lin & 31;
            wS[e * WSS + kk] = vp_w[(size_t)e * 256 + k0 + kk];
        }
        __syncthreads();
#pragma unroll
        for (int kk = 0; kk < 32; kk += 4) {
            float4 wv4[8], av4[4];
#pragma unroll
            for (int i = 0; i < 8; i++)
                wv4[i] = *(const float4*)&wS[(eg + 32 * i) * WSS + kk];
#pragma unroll
            for (int j = 0; j < 4; j++)
                av4[j] = *(const float4*)&sA[(pg * 4 + j) * SAS + k0 + kk];
#pragma unroll
            for (int j = 0; j < 4; j++)
#pragma unroll
                for (int i = 0; i < 8; i++)
                    acc[j][i] += av4[j].x * wv4[i].x + av4[j].y * wv4[i].y
                               + av4[j].z * wv4[i].z + av4[j].w * wv4[i].w;
        }
    }

    __syncthreads();
#pragma unroll
    for (int j = 0; j < 4; j++) {
        int p = pg * 4 + j;
#pragma unroll
        for (int i = 0; i < 8; i++) {
            int e = eg + 32 * i;
            float t = acc[j][i] + vp_b[e] + inst[(size_t)(p0 + p) * E_ + e];
            sA[p * SAS + e] = t;
            acc[j][i] = 0.f;
        }
    }

    for (int k0 = 0; k0 < 256; k0 += 32) {
        __syncthreads();
#pragma unroll
        for (int r = 0; r < 32; r++) {
            int lin = r * 256 + tid;
            int e = lin >> 5, kk = lin & 31;
            wS[e * WSS + kk] = op_w[(size_t)e * 256 + k0 + kk];
        }
        __syncthreads();
#pragma unroll
        for (int kk = 0; kk < 32; kk += 4) {
            float4 wv4[8], av4[4];
#pragma unroll
            for (int i = 0; i < 8; i++)
                wv4[i] = *(const float4*)&wS[(eg + 32 * i) * WSS + kk];
#pragma unroll
            for (int j = 0; j < 4; j++)
                av4[j] = *(const float4*)&sA[(pg * 4 + j) * SAS + k0 + kk];
#pragma unroll
            for (int j = 0; j < 4; j++)
#pragma unroll
                for (int i = 0; i < 8; i++)
                    acc[j][i] += av4[j].x * wv4[i].x + av4[j].y * wv4[i].y
                               + av4[j].z * wv4[i].z + av4[j].w * wv4[i].w;
        }
    }

#pragma unroll
    for (int j = 0; j < 4; j++) {
        int p = pg * 4 + j;
#pragma unroll
        for (int i = 0; i < 8; i++) {
            int e = eg + 32 * i;
            io[(size_t)(p0 + p) * E_ + e] = acc[j][i] + op_b[e];
        }
    }
}

// ---------------------------------------------------------------------------
extern "C" void kernel_launch(void* const* d_in, const int* in_sizes, int n_in,
                              void* d_out, int out_size, void* d_ws, size_t ws_size,
                              hipStream_t stream)
{
    const float* inst   = (const float*)d_in[0];
    const float* anchor = (const float*)d_in[1];
    const float* proj   = (const float*)d_in[2];
    const float* f0     = (const float*)d_in[3];
    const float* f1     = (const float*)d_in[4];
    const float* f2     = (const float*)d_in[5];
    const float* f3     = (const float*)d_in[6];
    const float* attn_w = (const float*)d_in[7];
    const float* attn_b = (const float*)d_in[8];
    const float* vp_w   = (const float*)d_in[9];
    const float* vp_b   = (const float*)d_in[10];
    const float* op_w   = (const float*)d_in[11];
    const float* op_b   = (const float*)d_in[12];
    float* out = (float*)d_out;

    // ws layout: meta_w (32 B/pt) | meta_b (16 B/pt) | partials (fp16, 39 MB)
    const size_t NPT = (size_t)B_ * C_ * N_;
    uint4* meta_w = (uint4*)d_ws;
    int4* meta_b = (int4*)((char*)d_ws + NPT * 32);
    __half2* part2 = (__half2*)((char*)d_ws + NPT * 48);
    const size_t part2_bytes = (size_t)B_ * C_ * SL2_ * N_ * sizeof(__half2);
    const size_t need = NPT * 48 + part2_bytes;

    prep_kernel<<<(B_ * N_) / 256, 256, 0, stream>>>(
        inst, anchor, proj, attn_w, attn_b, meta_w, meta_b);

    if (ws_size >= need) {
        gather_t<true><<<B_ * C_ * SL2_, 1024, 0, stream>>>(
            f0, f1, f2, f3, meta_w, meta_b, part2, out);
        gemm_mfma<<<(B_ * N_) / 128, 1024, 0, stream>>>(
            inst, vp_w, vp_b, op_w, op_b, part2, out);
    } else {
        hipMemsetAsync(d_out, 0, (size_t)out_size * sizeof(float), stream);
        gather_t<false><<<B_ * C_ * SL2_, 1024, 0, stream>>>(
            f0, f1, f2, f3, meta_w, meta_b, part2, out);
        gemm_valu<<<(B_ * N_) / PT, 256, 0, stream>>>(
            inst, vp_w, vp_b, op_w, op_b, out);
    }
}